// Round 1
// baseline (1201.625 us; speedup 1.0000x reference)
//
#include <hip/hip_runtime.h>
#include <hip/hip_bf16.h>

#define NEG_SLOPE 0.1f

// ---------------- CSR build ----------------
__global__ void hist_k(const int* __restrict__ dst, int* __restrict__ counts, int E) {
    int e = blockIdx.x * blockDim.x + threadIdx.x;
    if (e < E) atomicAdd(&counts[dst[e]], 1);
}

// single-block exclusive scan over counts[n] -> offs[n+1]
__global__ void scan_k(const int* __restrict__ counts, int* __restrict__ offs, int n) {
    __shared__ int partial[1024];
    int t = threadIdx.x;
    int chunk = (n + 1023) >> 10;
    int beg = t * chunk, end = min(beg + chunk, n);
    int s = 0;
    for (int i = beg; i < end; ++i) s += counts[i];
    partial[t] = s;
    __syncthreads();
    for (int off = 1; off < 1024; off <<= 1) {
        int v = (t >= off) ? partial[t - off] : 0;
        __syncthreads();
        partial[t] += v;
        __syncthreads();
    }
    int run = partial[t] - s;   // exclusive prefix for this chunk
    for (int i = beg; i < end; ++i) { offs[i] = run; run += counts[i]; }
    if (t == 1023) offs[n] = run;   // total = E
}

__global__ void scatter_k(const int* __restrict__ dst, const int* __restrict__ offs,
                          int* __restrict__ cursor, int* __restrict__ eidx, int E) {
    int e = blockIdx.x * blockDim.x + threadIdx.x;
    if (e >= E) return;
    int d = dst[e];
    int p = atomicAdd(&cursor[d], 1);
    eidx[offs[d] + p] = e;
}

// ---------------- GEMM: C[M,128] = [A0|A1][M,K] @ B[K,128] (+bias) ----------------
template<int K, bool BIAS>
__global__ __launch_bounds__(256) void gemm_fc(const float* __restrict__ A0,
                                               const float* __restrict__ A1,
                                               const float* __restrict__ B,
                                               const float* __restrict__ bias,
                                               float* __restrict__ C, int M) {
    __shared__ float As[16][68];    // padded, transposed: As[k][m]
    __shared__ float Bs[16][128];
    int t = threadIdx.x;
    int m0 = blockIdx.x * 64;
    int tx = t & 31, ty = t >> 5;
    float acc[8][4] = {};
    for (int k0 = 0; k0 < K; k0 += 16) {
        {   // stage A (64 rows x 16 k), transposed into As
            int row = t >> 2;            // 0..63
            int kq  = (t & 3) * 4;       // 0,4,8,12
            int gm = m0 + row;
            float4 v = make_float4(0.f, 0.f, 0.f, 0.f);
            if (gm < M) {
                int kg = k0 + kq;
                const float* sp = (K == 256 && kg >= 128) ? (A1 + gm * 128 + (kg - 128))
                                                          : (A0 + gm * 128 + kg);
                v = *(const float4*)sp;
            }
            As[kq + 0][row] = v.x; As[kq + 1][row] = v.y;
            As[kq + 2][row] = v.z; As[kq + 3][row] = v.w;
        }
        {   // stage B (16 rows x 128 cols)
            #pragma unroll
            for (int i = 0; i < 2; ++i) {
                int f = t + i * 256;         // 0..511 float4 slots
                int row = f >> 5;            // 0..15
                int c4 = (f & 31) * 4;
                *(float4*)&Bs[row][c4] = *(const float4*)(B + (k0 + row) * 128 + c4);
            }
        }
        __syncthreads();
        #pragma unroll
        for (int kk = 0; kk < 16; ++kk) {
            float4 b = *(const float4*)&Bs[kk][tx * 4];
            float a[8];
            #pragma unroll
            for (int j = 0; j < 8; ++j) a[j] = As[kk][ty * 8 + j];
            #pragma unroll
            for (int j = 0; j < 8; ++j) {
                acc[j][0] += a[j] * b.x; acc[j][1] += a[j] * b.y;
                acc[j][2] += a[j] * b.z; acc[j][3] += a[j] * b.w;
            }
        }
        __syncthreads();
    }
    #pragma unroll
    for (int j = 0; j < 8; ++j) {
        int gm = m0 + ty * 8 + j;
        if (gm < M) {
            float4 v = make_float4(acc[j][0], acc[j][1], acc[j][2], acc[j][3]);
            if (BIAS) {
                float4 bb = *(const float4*)(bias + tx * 4);
                v.x += bb.x; v.y += bb.y; v.z += bb.z; v.w += bb.w;
            }
            *(float4*)(C + gm * 128 + tx * 4) = v;
        }
    }
}

// ---------------- el/er: dot(ft[n,h,:], al[h,:]) ----------------
__global__ void elr_k(const float* __restrict__ ft, const float* __restrict__ al,
                      const float* __restrict__ ar, float* __restrict__ el,
                      float* __restrict__ er, int n) {
    int idx = blockIdx.x * blockDim.x + threadIdx.x;   // one per (node, head)
    if (idx >= n * 8) return;
    int node = idx >> 3, h = idx & 7;
    const float* f = ft + node * 128 + h * 16;
    const float* a = al + h * 16;
    const float* b = ar + h * 16;
    float e1 = 0.f, e2 = 0.f;
    #pragma unroll
    for (int d = 0; d < 16; ++d) { float fv = f[d]; e1 += fv * a[d]; e2 += fv * b[d]; }
    el[idx] = e1; er[idx] = e2;
}

// ---------------- aggregation: one wave per dst node ----------------
__global__ __launch_bounds__(256) void agg_k(const float* __restrict__ ft,
                                             const float* __restrict__ el,
                                             const float* __restrict__ er,
                                             const float* __restrict__ w,
                                             const int* __restrict__ src,
                                             const int* __restrict__ offs,
                                             const int* __restrict__ eidx,
                                             float* __restrict__ out, int n) {
    int node = blockIdx.x * 4 + (threadIdx.x >> 6);
    if (node >= n) return;
    int lane = threadIdx.x & 63;
    int h8 = lane & 7;     // head for score passes
    int g8 = lane >> 3;    // edge-group for score passes; also head for agg pass
    int beg = offs[node], end = offs[node + 1];
    float er_s = er[node * 8 + h8];

    // pass 1: per-head max
    float mx = -INFINITY;
    for (int j = beg + g8; j < end; j += 8) {
        int e = eidx[j];
        float v = el[src[e] * 8 + h8] + er_s;
        v = v > 0.f ? v : NEG_SLOPE * v;
        v *= w[e];
        mx = fmaxf(mx, v);
    }
    mx = fmaxf(mx, __shfl_xor(mx, 8));
    mx = fmaxf(mx, __shfl_xor(mx, 16));
    mx = fmaxf(mx, __shfl_xor(mx, 32));

    // pass 2: sum of exp
    float sum = 0.f;
    for (int j = beg + g8; j < end; j += 8) {
        int e = eidx[j];
        float v = el[src[e] * 8 + h8] + er_s;
        v = v > 0.f ? v : NEG_SLOPE * v;
        v *= w[e];
        sum += __expf(v - mx);
    }
    sum += __shfl_xor(sum, 8);
    sum += __shfl_xor(sum, 16);
    sum += __shfl_xor(sum, 32);

    // redistribute to agg layout: lane owns output dims 2*lane, 2*lane+1 -> head lane>>3
    float mA = __shfl(mx, g8);          // lane g8 holds head g8 stats
    float sA = __shfl(sum, g8);
    float inv_s = (sA > 0.f) ? 1.f / sA : 0.f;
    float er_a = er[node * 8 + g8];

    float acc0 = 0.f, acc1 = 0.f;
    for (int j = beg; j < end; ++j) {
        int e = eidx[j];
        int sn = src[e];
        float v = el[sn * 8 + g8] + er_a;
        v = v > 0.f ? v : NEG_SLOPE * v;
        v *= w[e];
        float a = __expf(v - mA) * inv_s;
        float2 f = *(const float2*)(ft + sn * 128 + lane * 2);
        acc0 += a * f.x;
        acc1 += a * f.y;
    }
    acc0 = fmaxf(acc0, 0.f);   // relu
    acc1 = fmaxf(acc1, 0.f);
    *(float2*)(out + node * 128 + lane * 2) = make_float2(acc0, acc1);
}

extern "C" void kernel_launch(void* const* d_in, const int* in_sizes, int n_in,
                              void* d_out, int out_size, void* d_ws, size_t ws_size,
                              hipStream_t stream) {
    const float* features = (const float*)d_in[0];
    const int*   src      = (const int*)d_in[1];
    const int*   dst      = (const int*)d_in[2];
    const float* w        = (const float*)d_in[3];
    const float* W1       = (const float*)d_in[4];
    const float* al1      = (const float*)d_in[5];
    const float* ar1      = (const float*)d_in[6];
    const float* W2       = (const float*)d_in[7];
    const float* al2      = (const float*)d_in[8];
    const float* ar2      = (const float*)d_in[9];
    const float* Wm       = (const float*)d_in[10];
    const float* bm       = (const float*)d_in[11];
    float* out = (float*)d_out;

    const int N = in_sizes[0] / 128;
    const int E = in_sizes[1];

    float* ws = (float*)d_ws;
    float* ft = ws;                       // N*128
    float* x1 = ft + (size_t)N * 128;     // N*128
    float* x2 = x1 + (size_t)N * 128;     // N*128
    float* el = x2 + (size_t)N * 128;     // N*8
    float* er = el + (size_t)N * 8;       // N*8
    int* counts = (int*)(er + (size_t)N * 8);   // N
    int* cursor = counts + N;                   // N
    int* offs   = cursor + N;                   // N+1
    int* eidx   = offs + N + 1;                 // E

    hipMemsetAsync(counts, 0, (size_t)N * sizeof(int), stream);
    hipMemsetAsync(cursor, 0, (size_t)N * sizeof(int), stream);

    // CSR build (dst shared by both layers)
    hist_k<<<(E + 255) / 256, 256, 0, stream>>>(dst, counts, E);
    scan_k<<<1, 1024, 0, stream>>>(counts, offs, N);
    scatter_k<<<(E + 255) / 256, 256, 0, stream>>>(dst, offs, cursor, eidx, E);

    int gemm_grid = (N + 63) / 64;

    // ---- layer 1 ----
    gemm_fc<128, false><<<gemm_grid, 256, 0, stream>>>(features, nullptr, W1, nullptr, ft, N);
    elr_k<<<(N * 8 + 255) / 256, 256, 0, stream>>>(ft, al1, ar1, el, er, N);
    agg_k<<<(N + 3) / 4, 256, 0, stream>>>(ft, el, er, w, src, offs, eidx, x1, N);

    // ---- layer 2 ----
    gemm_fc<128, false><<<gemm_grid, 256, 0, stream>>>(x1, nullptr, W2, nullptr, ft, N);
    elr_k<<<(N * 8 + 255) / 256, 256, 0, stream>>>(ft, al2, ar2, el, er, N);
    agg_k<<<(N + 3) / 4, 256, 0, stream>>>(ft, el, er, w, src, offs, eidx, x2, N);

    // ---- final: [x1|x2] @ Wm + bm ----
    gemm_fc<256, true><<<gemm_grid, 256, 0, stream>>>(x1, x2, Wm, bm, out, N);
}

// Round 2
// 693.899 us; speedup vs baseline: 1.7317x; 1.7317x over previous
//
#include <hip/hip_runtime.h>
#include <hip/hip_bf16.h>

#define NEG_SLOPE 0.1f

__device__ __forceinline__ float bf2f(unsigned u) { return __uint_as_float(u << 16); }
__device__ __forceinline__ unsigned short f2bf(float f) {
    __hip_bfloat16 h = __float2bfloat16(f);
    unsigned short r;
    __builtin_memcpy(&r, &h, 2);
    return r;
}

// ---------------- CSR build ----------------
__global__ void hist_k(const int* __restrict__ dst, int* __restrict__ counts, int E) {
    int e = blockIdx.x * blockDim.x + threadIdx.x;
    if (e < E) atomicAdd(&counts[dst[e]], 1);
}

// single-block exclusive scan over counts[n] -> offs[n+1]
__global__ void scan_k(const int* __restrict__ counts, int* __restrict__ offs, int n) {
    __shared__ int partial[1024];
    int t = threadIdx.x;
    int chunk = (n + 1023) >> 10;
    int beg = t * chunk, end = min(beg + chunk, n);
    int s = 0;
    for (int i = beg; i < end; ++i) s += counts[i];
    partial[t] = s;
    __syncthreads();
    for (int off = 1; off < 1024; off <<= 1) {
        int v = (t >= off) ? partial[t - off] : 0;
        __syncthreads();
        partial[t] += v;
        __syncthreads();
    }
    int run = partial[t] - s;   // exclusive prefix for this chunk
    for (int i = beg; i < end; ++i) { offs[i] = run; run += counts[i]; }
    if (t == 1023) offs[n] = run;   // total = E
}

// scatter (src, w) into CSR order so agg reads them coalesced
__global__ void scatter_k(const int* __restrict__ src, const int* __restrict__ dst,
                          const float* __restrict__ w, const int* __restrict__ offs,
                          int* __restrict__ cursor, int2* __restrict__ snw, int E) {
    int e = blockIdx.x * blockDim.x + threadIdx.x;
    if (e >= E) return;
    int d = dst[e];
    int p = atomicAdd(&cursor[d], 1);
    snw[offs[d] + p] = make_int2(src[e], __float_as_int(w[e]));
}

// ---------------- GEMM: C[M,128] = [A0|A1][M,K] @ B[K,128] (+bias) ----------------
template<int K, bool BIAS, bool OUT_BF16>
__global__ __launch_bounds__(256) void gemm_fc(const float* __restrict__ A0,
                                               const float* __restrict__ A1,
                                               const float* __restrict__ B,
                                               const float* __restrict__ bias,
                                               void* __restrict__ Cv, int M) {
    __shared__ float As[16][68];    // padded, transposed: As[k][m]
    __shared__ float Bs[16][128];
    int t = threadIdx.x;
    int m0 = blockIdx.x * 64;
    int tx = t & 31, ty = t >> 5;
    float acc[8][4] = {};
    for (int k0 = 0; k0 < K; k0 += 16) {
        {   // stage A (64 rows x 16 k), transposed into As
            int row = t >> 2;            // 0..63
            int kq  = (t & 3) * 4;       // 0,4,8,12
            int gm = m0 + row;
            float4 v = make_float4(0.f, 0.f, 0.f, 0.f);
            if (gm < M) {
                int kg = k0 + kq;
                const float* sp = (K == 256 && kg >= 128) ? (A1 + gm * 128 + (kg - 128))
                                                          : (A0 + gm * 128 + kg);
                v = *(const float4*)sp;
            }
            As[kq + 0][row] = v.x; As[kq + 1][row] = v.y;
            As[kq + 2][row] = v.z; As[kq + 3][row] = v.w;
        }
        {   // stage B (16 rows x 128 cols)
            #pragma unroll
            for (int i = 0; i < 2; ++i) {
                int f = t + i * 256;         // 0..511 float4 slots
                int row = f >> 5;            // 0..15
                int c4 = (f & 31) * 4;
                *(float4*)&Bs[row][c4] = *(const float4*)(B + (k0 + row) * 128 + c4);
            }
        }
        __syncthreads();
        #pragma unroll
        for (int kk = 0; kk < 16; ++kk) {
            float4 b = *(const float4*)&Bs[kk][tx * 4];
            float a[8];
            #pragma unroll
            for (int j = 0; j < 8; ++j) a[j] = As[kk][ty * 8 + j];
            #pragma unroll
            for (int j = 0; j < 8; ++j) {
                acc[j][0] += a[j] * b.x; acc[j][1] += a[j] * b.y;
                acc[j][2] += a[j] * b.z; acc[j][3] += a[j] * b.w;
            }
        }
        __syncthreads();
    }
    #pragma unroll
    for (int j = 0; j < 8; ++j) {
        int gm = m0 + ty * 8 + j;
        if (gm < M) {
            float4 v = make_float4(acc[j][0], acc[j][1], acc[j][2], acc[j][3]);
            if (BIAS) {
                float4 bb = *(const float4*)(bias + tx * 4);
                v.x += bb.x; v.y += bb.y; v.z += bb.z; v.w += bb.w;
            }
            if (OUT_BF16) {
                ushort4 s;
                s.x = f2bf(v.x); s.y = f2bf(v.y); s.z = f2bf(v.z); s.w = f2bf(v.w);
                *(ushort4*)((__hip_bfloat16*)Cv + (size_t)gm * 128 + tx * 4) = s;
            } else {
                *(float4*)((float*)Cv + (size_t)gm * 128 + tx * 4) = v;
            }
        }
    }
}

// ---------------- el/er: dot(ft[n,h,:], al[h,:]) (bf16 in, bf16 out) ----------------
__global__ void elr_k(const __hip_bfloat16* __restrict__ ft, const float* __restrict__ al,
                      const float* __restrict__ ar, __hip_bfloat16* __restrict__ el,
                      __hip_bfloat16* __restrict__ er, int n) {
    int idx = blockIdx.x * blockDim.x + threadIdx.x;   // one per (node, head)
    if (idx >= n * 8) return;
    int node = idx >> 3, h = idx & 7;
    const __hip_bfloat16* f = ft + (size_t)node * 128 + h * 16;
    uint4 a = *(const uint4*)f;        // bf16 x8
    uint4 b = *(const uint4*)(f + 8);  // bf16 x8
    float fv[16];
    fv[0]  = bf2f(a.x & 0xffff); fv[1]  = bf2f(a.x >> 16);
    fv[2]  = bf2f(a.y & 0xffff); fv[3]  = bf2f(a.y >> 16);
    fv[4]  = bf2f(a.z & 0xffff); fv[5]  = bf2f(a.z >> 16);
    fv[6]  = bf2f(a.w & 0xffff); fv[7]  = bf2f(a.w >> 16);
    fv[8]  = bf2f(b.x & 0xffff); fv[9]  = bf2f(b.x >> 16);
    fv[10] = bf2f(b.y & 0xffff); fv[11] = bf2f(b.y >> 16);
    fv[12] = bf2f(b.z & 0xffff); fv[13] = bf2f(b.z >> 16);
    fv[14] = bf2f(b.w & 0xffff); fv[15] = bf2f(b.w >> 16);
    float e1 = 0.f, e2 = 0.f;
    #pragma unroll
    for (int d = 0; d < 16; ++d) { e1 += fv[d] * al[h * 16 + d]; e2 += fv[d] * ar[h * 16 + d]; }
    unsigned short r1 = f2bf(e1), r2 = f2bf(e2);
    __builtin_memcpy(&el[idx], &r1, 2);
    __builtin_memcpy(&er[idx], &r2, 2);
}

// ---------------- aggregation: one wave per dst node ----------------
// scores computed once (lane-per-edge, 8 heads/lane), exp without max shift
// (|score| <= ~2.5 here; softmax is shift-invariant), normalization at the end.
__global__ __launch_bounds__(256) void agg_k(const __hip_bfloat16* __restrict__ ftb,
                                             const __hip_bfloat16* __restrict__ el,
                                             const __hip_bfloat16* __restrict__ er,
                                             const int2* __restrict__ snw,
                                             const int* __restrict__ offs,
                                             float* __restrict__ out, int n) {
    __shared__ float pbuf[4][64][9];   // [wave][edge][head], pad 9: 2-way banks (free)
    __shared__ int   snbuf[4][64];
    int wid = threadIdx.x >> 6;
    int node = blockIdx.x * 4 + wid;
    if (node >= n) return;
    int lane = threadIdx.x & 63;
    int g8 = lane >> 3;                // head this lane aggregates
    int beg = offs[node], end = offs[node + 1];
    int deg = end - beg;

    // er for this node (uniform): 8 bf16 = 16B
    float erv[8];
    {
        uint4 u = *(const uint4*)(er + (size_t)node * 8);
        erv[0] = bf2f(u.x & 0xffff); erv[1] = bf2f(u.x >> 16);
        erv[2] = bf2f(u.y & 0xffff); erv[3] = bf2f(u.y >> 16);
        erv[4] = bf2f(u.z & 0xffff); erv[5] = bf2f(u.z >> 16);
        erv[6] = bf2f(u.w & 0xffff); erv[7] = bf2f(u.w >> 16);
    }

    float spart[8];
    #pragma unroll
    for (int h = 0; h < 8; ++h) spart[h] = 0.f;
    float acc0 = 0.f, acc1 = 0.f;

    for (int c0 = 0; c0 < deg; c0 += 64) {
        int cnt = min(64, deg - c0);
        bool act = lane < cnt;
        int sn = 0; float wv = 0.f;
        float elv[8];
        #pragma unroll
        for (int h = 0; h < 8; ++h) elv[h] = 0.f;
        if (act) {
            int2 p2 = snw[beg + c0 + lane];     // coalesced 8B
            sn = p2.x; wv = __int_as_float(p2.y);
            uint4 u = *(const uint4*)(el + (size_t)sn * 8);  // L2-resident gather
            elv[0] = bf2f(u.x & 0xffff); elv[1] = bf2f(u.x >> 16);
            elv[2] = bf2f(u.y & 0xffff); elv[3] = bf2f(u.y >> 16);
            elv[4] = bf2f(u.z & 0xffff); elv[5] = bf2f(u.z >> 16);
            elv[6] = bf2f(u.w & 0xffff); elv[7] = bf2f(u.w >> 16);
        }
        float p[8];
        #pragma unroll
        for (int h = 0; h < 8; ++h) {
            float t = elv[h] + erv[h];
            t = t > 0.f ? t : NEG_SLOPE * t;
            t *= wv;
            p[h] = act ? __expf(t) : 0.f;
            spart[h] += p[h];
        }
        snbuf[wid][lane] = sn;
        #pragma unroll
        for (int h = 0; h < 8; ++h) pbuf[wid][lane][h] = p[h];
        __builtin_amdgcn_wave_barrier();
        asm volatile("s_waitcnt lgkmcnt(0)" ::: "memory");
        __builtin_amdgcn_wave_barrier();

        // aggregate this chunk: lane owns output dims 2*lane, 2*lane+1 of head g8
        #pragma unroll 4
        for (int j = 0; j < cnt; ++j) {
            int sj = snbuf[wid][j];                       // broadcast
            float a = pbuf[wid][j][g8];                   // 8-way broadcast, conflict-free
            unsigned u = *(const unsigned*)(ftb + (size_t)sj * 128 + lane * 2);  // 256B/row coalesced
            acc0 += a * bf2f(u & 0xffff);
            acc1 += a * bf2f(u >> 16);
        }
        __builtin_amdgcn_wave_barrier();
    }

    // total sum per head (butterfly over 64 lanes)
    #pragma unroll
    for (int h = 0; h < 8; ++h) {
        float t = spart[h];
        t += __shfl_xor(t, 1);  t += __shfl_xor(t, 2);  t += __shfl_xor(t, 4);
        t += __shfl_xor(t, 8);  t += __shfl_xor(t, 16); t += __shfl_xor(t, 32);
        spart[h] = t;
    }
    // compile-time select of spart[g8]
    float sg = (g8 & 4) ? ((g8 & 2) ? ((g8 & 1) ? spart[7] : spart[6])
                                    : ((g8 & 1) ? spart[5] : spart[4]))
                        : ((g8 & 2) ? ((g8 & 1) ? spart[3] : spart[2])
                                    : ((g8 & 1) ? spart[1] : spart[0]));
    float sinv = sg > 0.f ? 1.f / sg : 0.f;
    float o0 = fmaxf(acc0 * sinv, 0.f);
    float o1 = fmaxf(acc1 * sinv, 0.f);
    *(float2*)(out + (size_t)node * 128 + lane * 2) = make_float2(o0, o1);
}

extern "C" void kernel_launch(void* const* d_in, const int* in_sizes, int n_in,
                              void* d_out, int out_size, void* d_ws, size_t ws_size,
                              hipStream_t stream) {
    const float* features = (const float*)d_in[0];
    const int*   src      = (const int*)d_in[1];
    const int*   dst      = (const int*)d_in[2];
    const float* w        = (const float*)d_in[3];
    const float* W1       = (const float*)d_in[4];
    const float* al1      = (const float*)d_in[5];
    const float* ar1      = (const float*)d_in[6];
    const float* W2       = (const float*)d_in[7];
    const float* al2      = (const float*)d_in[8];
    const float* ar2      = (const float*)d_in[9];
    const float* Wm       = (const float*)d_in[10];
    const float* bm       = (const float*)d_in[11];
    float* out = (float*)d_out;

    const int N = in_sizes[0] / 128;
    const int E = in_sizes[1];

    char* ws = (char*)d_ws;
    __hip_bfloat16* ftb = (__hip_bfloat16*)ws;            ws += (size_t)N * 128 * 2;
    float* x1 = (float*)ws;                               ws += (size_t)N * 128 * 4;
    float* x2 = (float*)ws;                               ws += (size_t)N * 128 * 4;
    __hip_bfloat16* el = (__hip_bfloat16*)ws;             ws += (size_t)N * 8 * 2;
    __hip_bfloat16* er = (__hip_bfloat16*)ws;             ws += (size_t)N * 8 * 2;
    int* counts = (int*)ws;                               ws += (size_t)N * 4;
    int* cursor = (int*)ws;                               ws += (size_t)N * 4;
    int* offs   = (int*)ws;                               ws += (size_t)(N + 4) * 4;
    int2* snw   = (int2*)ws;                              ws += (size_t)E * 8;

    hipMemsetAsync(counts, 0, (size_t)N * sizeof(int), stream);
    hipMemsetAsync(cursor, 0, (size_t)N * sizeof(int), stream);

    // CSR build (dst shared by both layers); (src,w) scattered into CSR order
    hist_k<<<(E + 255) / 256, 256, 0, stream>>>(dst, counts, E);
    scan_k<<<1, 1024, 0, stream>>>(counts, offs, N);
    scatter_k<<<(E + 255) / 256, 256, 0, stream>>>(src, dst, w, offs, cursor, snw, E);

    int gemm_grid = (N + 63) / 64;
    int agg_grid = (N + 3) / 4;

    // ---- layer 1 ----
    gemm_fc<128, false, true><<<gemm_grid, 256, 0, stream>>>(features, nullptr, W1, nullptr, ftb, N);
    elr_k<<<(N * 8 + 255) / 256, 256, 0, stream>>>(ftb, al1, ar1, el, er, N);
    agg_k<<<agg_grid, 256, 0, stream>>>(ftb, el, er, snw, offs, x1, N);

    // ---- layer 2 ----
    gemm_fc<128, false, true><<<gemm_grid, 256, 0, stream>>>(x1, nullptr, W2, nullptr, ftb, N);
    elr_k<<<(N * 8 + 255) / 256, 256, 0, stream>>>(ftb, al2, ar2, el, er, N);
    agg_k<<<agg_grid, 256, 0, stream>>>(ftb, el, er, snw, offs, x2, N);

    // ---- final: [x1|x2] @ Wm + bm ----
    gemm_fc<256, true, false><<<gemm_grid, 256, 0, stream>>>(x1, x2, Wm, bm, out, N);
}

// Round 3
// 546.652 us; speedup vs baseline: 2.1982x; 1.2694x over previous
//
#include <hip/hip_runtime.h>
#include <hip/hip_bf16.h>

#define NEG_SLOPE 0.1f
#define SCAN_TILE 1024

__device__ __forceinline__ float bf2f(unsigned u) { return __uint_as_float(u << 16); }
__device__ __forceinline__ unsigned short f2bf(float f) {
    __hip_bfloat16 h = __float2bfloat16(f);
    unsigned short r;
    __builtin_memcpy(&r, &h, 2);
    return r;
}

// ---------------- CSR build ----------------
__global__ void hist_k(const int* __restrict__ dst, int* __restrict__ counts, int E) {
    int e = blockIdx.x * blockDim.x + threadIdx.x;
    if (e < E) atomicAdd(&counts[dst[e]], 1);
}

// phase 1: per-block (1024-elem tile) sum -> blocksums
__global__ __launch_bounds__(256) void scan_reduce_k(const int* __restrict__ counts,
                                                     int* __restrict__ blocksums, int n) {
    __shared__ int sdata[256];
    int t = threadIdx.x;
    int idx0 = blockIdx.x * SCAN_TILE + t * 4;
    int4 c = make_int4(0, 0, 0, 0);
    if (idx0 + 3 < n) c = *(const int4*)(counts + idx0);
    else {
        if (idx0     < n) c.x = counts[idx0];
        if (idx0 + 1 < n) c.y = counts[idx0 + 1];
        if (idx0 + 2 < n) c.z = counts[idx0 + 2];
        if (idx0 + 3 < n) c.w = counts[idx0 + 3];
    }
    sdata[t] = c.x + c.y + c.z + c.w;
    __syncthreads();
    for (int off = 128; off > 0; off >>= 1) {
        if (t < off) sdata[t] += sdata[t + off];
        __syncthreads();
    }
    if (t == 0) blocksums[blockIdx.x] = sdata[0];
}

// phase 2: single-block exclusive scan of blocksums (nb <= 1024)
__global__ __launch_bounds__(1024) void scan_spine_k(int* __restrict__ blocksums, int nb) {
    __shared__ int buf[1024];
    int t = threadIdx.x;
    int v = (t < nb) ? blocksums[t] : 0;
    buf[t] = v;
    __syncthreads();
    for (int off = 1; off < 1024; off <<= 1) {
        int u = (t >= off) ? buf[t - off] : 0;
        __syncthreads();
        buf[t] += u;
        __syncthreads();
    }
    if (t < nb) blocksums[t] = buf[t] - v;   // exclusive
}

// phase 3: per-block rescan + write offs; offs[n] = E (known)
__global__ __launch_bounds__(256) void scan_final_k(const int* __restrict__ counts,
                                                    const int* __restrict__ blocksums,
                                                    int* __restrict__ offs, int n, int E) {
    __shared__ int buf[256];
    int t = threadIdx.x;
    int idx0 = blockIdx.x * SCAN_TILE + t * 4;
    int4 c = make_int4(0, 0, 0, 0);
    if (idx0 + 3 < n) c = *(const int4*)(counts + idx0);
    else {
        if (idx0     < n) c.x = counts[idx0];
        if (idx0 + 1 < n) c.y = counts[idx0 + 1];
        if (idx0 + 2 < n) c.z = counts[idx0 + 2];
        if (idx0 + 3 < n) c.w = counts[idx0 + 3];
    }
    int s = c.x + c.y + c.z + c.w;
    buf[t] = s;
    __syncthreads();
    for (int off = 1; off < 256; off <<= 1) {
        int u = (t >= off) ? buf[t - off] : 0;
        __syncthreads();
        buf[t] += u;
        __syncthreads();
    }
    int o0 = buf[t] - s + blocksums[blockIdx.x];
    int o1 = o0 + c.x, o2 = o1 + c.y, o3 = o2 + c.z;
    if (idx0 + 3 < n) *(int4*)(offs + idx0) = make_int4(o0, o1, o2, o3);
    else {
        if (idx0     < n) offs[idx0]     = o0;
        if (idx0 + 1 < n) offs[idx0 + 1] = o1;
        if (idx0 + 2 < n) offs[idx0 + 2] = o2;
    }
    if (blockIdx.x == 0 && t == 0) offs[n] = E;
}

// scatter (src, w) into CSR order so agg reads them coalesced
__global__ void scatter_k(const int* __restrict__ src, const int* __restrict__ dst,
                          const float* __restrict__ w, const int* __restrict__ offs,
                          int* __restrict__ cursor, int2* __restrict__ snw, int E) {
    int e = blockIdx.x * blockDim.x + threadIdx.x;
    if (e >= E) return;
    int d = dst[e];
    int p = atomicAdd(&cursor[d], 1);
    snw[offs[d] + p] = make_int2(src[e], __float_as_int(w[e]));
}

// ---------------- GEMM: C[M,128] = [A0|A1][M,K] @ B[K,128] (+bias) ----------------
template<int K, bool BIAS, bool OUT_BF16>
__global__ __launch_bounds__(256) void gemm_fc(const float* __restrict__ A0,
                                               const float* __restrict__ A1,
                                               const float* __restrict__ B,
                                               const float* __restrict__ bias,
                                               void* __restrict__ Cv, int M) {
    __shared__ float As[16][68];    // padded, transposed: As[k][m]
    __shared__ float Bs[16][128];
    int t = threadIdx.x;
    int m0 = blockIdx.x * 64;
    int tx = t & 31, ty = t >> 5;
    float acc[8][4] = {};
    for (int k0 = 0; k0 < K; k0 += 16) {
        {   // stage A (64 rows x 16 k), transposed into As
            int row = t >> 2;            // 0..63
            int kq  = (t & 3) * 4;       // 0,4,8,12
            int gm = m0 + row;
            float4 v = make_float4(0.f, 0.f, 0.f, 0.f);
            if (gm < M) {
                int kg = k0 + kq;
                const float* sp = (K == 256 && kg >= 128) ? (A1 + gm * 128 + (kg - 128))
                                                          : (A0 + gm * 128 + kg);
                v = *(const float4*)sp;
            }
            As[kq + 0][row] = v.x; As[kq + 1][row] = v.y;
            As[kq + 2][row] = v.z; As[kq + 3][row] = v.w;
        }
        {   // stage B (16 rows x 128 cols)
            #pragma unroll
            for (int i = 0; i < 2; ++i) {
                int f = t + i * 256;         // 0..511 float4 slots
                int row = f >> 5;            // 0..15
                int c4 = (f & 31) * 4;
                *(float4*)&Bs[row][c4] = *(const float4*)(B + (k0 + row) * 128 + c4);
            }
        }
        __syncthreads();
        #pragma unroll
        for (int kk = 0; kk < 16; ++kk) {
            float4 b = *(const float4*)&Bs[kk][tx * 4];
            float a[8];
            #pragma unroll
            for (int j = 0; j < 8; ++j) a[j] = As[kk][ty * 8 + j];
            #pragma unroll
            for (int j = 0; j < 8; ++j) {
                acc[j][0] += a[j] * b.x; acc[j][1] += a[j] * b.y;
                acc[j][2] += a[j] * b.z; acc[j][3] += a[j] * b.w;
            }
        }
        __syncthreads();
    }
    #pragma unroll
    for (int j = 0; j < 8; ++j) {
        int gm = m0 + ty * 8 + j;
        if (gm < M) {
            float4 v = make_float4(acc[j][0], acc[j][1], acc[j][2], acc[j][3]);
            if (BIAS) {
                float4 bb = *(const float4*)(bias + tx * 4);
                v.x += bb.x; v.y += bb.y; v.z += bb.z; v.w += bb.w;
            }
            if (OUT_BF16) {
                ushort4 s;
                s.x = f2bf(v.x); s.y = f2bf(v.y); s.z = f2bf(v.z); s.w = f2bf(v.w);
                *(ushort4*)((__hip_bfloat16*)Cv + (size_t)gm * 128 + tx * 4) = s;
            } else {
                *(float4*)((float*)Cv + (size_t)gm * 128 + tx * 4) = v;
            }
        }
    }
}

// ---------------- el/er: dot(ft[n,h,:], al[h,:]) (bf16 in, bf16 out) ----------------
__global__ void elr_k(const __hip_bfloat16* __restrict__ ft, const float* __restrict__ al,
                      const float* __restrict__ ar, __hip_bfloat16* __restrict__ el,
                      __hip_bfloat16* __restrict__ er, int n) {
    int idx = blockIdx.x * blockDim.x + threadIdx.x;   // one per (node, head)
    if (idx >= n * 8) return;
    int node = idx >> 3, h = idx & 7;
    const __hip_bfloat16* f = ft + (size_t)node * 128 + h * 16;
    uint4 a = *(const uint4*)f;        // bf16 x8
    uint4 b = *(const uint4*)(f + 8);  // bf16 x8
    float fv[16];
    fv[0]  = bf2f(a.x & 0xffff); fv[1]  = bf2f(a.x >> 16);
    fv[2]  = bf2f(a.y & 0xffff); fv[3]  = bf2f(a.y >> 16);
    fv[4]  = bf2f(a.z & 0xffff); fv[5]  = bf2f(a.z >> 16);
    fv[6]  = bf2f(a.w & 0xffff); fv[7]  = bf2f(a.w >> 16);
    fv[8]  = bf2f(b.x & 0xffff); fv[9]  = bf2f(b.x >> 16);
    fv[10] = bf2f(b.y & 0xffff); fv[11] = bf2f(b.y >> 16);
    fv[12] = bf2f(b.z & 0xffff); fv[13] = bf2f(b.z >> 16);
    fv[14] = bf2f(b.w & 0xffff); fv[15] = bf2f(b.w >> 16);
    float e1 = 0.f, e2 = 0.f;
    #pragma unroll
    for (int d = 0; d < 16; ++d) { e1 += fv[d] * al[h * 16 + d]; e2 += fv[d] * ar[h * 16 + d]; }
    unsigned short r1 = f2bf(e1), r2 = f2bf(e2);
    __builtin_memcpy(&el[idx], &r1, 2);
    __builtin_memcpy(&er[idx], &r2, 2);
}

// ---------------- aggregation: one wave per dst node ----------------
__global__ __launch_bounds__(256) void agg_k(const __hip_bfloat16* __restrict__ ftb,
                                             const __hip_bfloat16* __restrict__ el,
                                             const __hip_bfloat16* __restrict__ er,
                                             const int2* __restrict__ snw,
                                             const int* __restrict__ offs,
                                             float* __restrict__ out, int n) {
    __shared__ float pbuf[4][64][9];   // [wave][edge][head], pad 9: 2-way banks (free)
    __shared__ int   snbuf[4][64];
    int wid = threadIdx.x >> 6;
    int node = blockIdx.x * 4 + wid;
    if (node >= n) return;
    int lane = threadIdx.x & 63;
    int g8 = lane >> 3;                // head this lane aggregates
    int beg = offs[node], end = offs[node + 1];
    int deg = end - beg;

    float erv[8];
    {
        uint4 u = *(const uint4*)(er + (size_t)node * 8);
        erv[0] = bf2f(u.x & 0xffff); erv[1] = bf2f(u.x >> 16);
        erv[2] = bf2f(u.y & 0xffff); erv[3] = bf2f(u.y >> 16);
        erv[4] = bf2f(u.z & 0xffff); erv[5] = bf2f(u.z >> 16);
        erv[6] = bf2f(u.w & 0xffff); erv[7] = bf2f(u.w >> 16);
    }

    float spart[8];
    #pragma unroll
    for (int h = 0; h < 8; ++h) spart[h] = 0.f;
    float acc0 = 0.f, acc1 = 0.f;

    for (int c0 = 0; c0 < deg; c0 += 64) {
        int cnt = min(64, deg - c0);
        bool act = lane < cnt;
        int sn = 0; float wv = 0.f;
        float elv[8];
        #pragma unroll
        for (int h = 0; h < 8; ++h) elv[h] = 0.f;
        if (act) {
            int2 p2 = snw[beg + c0 + lane];     // coalesced 8B
            sn = p2.x; wv = __int_as_float(p2.y);
            uint4 u = *(const uint4*)(el + (size_t)sn * 8);  // L2-resident gather
            elv[0] = bf2f(u.x & 0xffff); elv[1] = bf2f(u.x >> 16);
            elv[2] = bf2f(u.y & 0xffff); elv[3] = bf2f(u.y >> 16);
            elv[4] = bf2f(u.z & 0xffff); elv[5] = bf2f(u.z >> 16);
            elv[6] = bf2f(u.w & 0xffff); elv[7] = bf2f(u.w >> 16);
        }
        float p[8];
        #pragma unroll
        for (int h = 0; h < 8; ++h) {
            float t = elv[h] + erv[h];
            t = t > 0.f ? t : NEG_SLOPE * t;
            t *= wv;
            p[h] = act ? __expf(t) : 0.f;
            spart[h] += p[h];
        }
        snbuf[wid][lane] = sn;
        #pragma unroll
        for (int h = 0; h < 8; ++h) pbuf[wid][lane][h] = p[h];
        __builtin_amdgcn_wave_barrier();
        asm volatile("s_waitcnt lgkmcnt(0)" ::: "memory");
        __builtin_amdgcn_wave_barrier();

        #pragma unroll 4
        for (int j = 0; j < cnt; ++j) {
            int sj = snbuf[wid][j];                       // broadcast
            float a = pbuf[wid][j][g8];                   // 8-way broadcast, conflict-free
            unsigned u = *(const unsigned*)(ftb + (size_t)sj * 128 + lane * 2);  // 256B/row coalesced
            acc0 += a * bf2f(u & 0xffff);
            acc1 += a * bf2f(u >> 16);
        }
        __builtin_amdgcn_wave_barrier();
    }

    #pragma unroll
    for (int h = 0; h < 8; ++h) {
        float t = spart[h];
        t += __shfl_xor(t, 1);  t += __shfl_xor(t, 2);  t += __shfl_xor(t, 4);
        t += __shfl_xor(t, 8);  t += __shfl_xor(t, 16); t += __shfl_xor(t, 32);
        spart[h] = t;
    }
    float sg = (g8 & 4) ? ((g8 & 2) ? ((g8 & 1) ? spart[7] : spart[6])
                                    : ((g8 & 1) ? spart[5] : spart[4]))
                        : ((g8 & 2) ? ((g8 & 1) ? spart[3] : spart[2])
                                    : ((g8 & 1) ? spart[1] : spart[0]));
    float sinv = sg > 0.f ? 1.f / sg : 0.f;
    float o0 = fmaxf(acc0 * sinv, 0.f);
    float o1 = fmaxf(acc1 * sinv, 0.f);
    *(float2*)(out + (size_t)node * 128 + lane * 2) = make_float2(o0, o1);
}

extern "C" void kernel_launch(void* const* d_in, const int* in_sizes, int n_in,
                              void* d_out, int out_size, void* d_ws, size_t ws_size,
                              hipStream_t stream) {
    const float* features = (const float*)d_in[0];
    const int*   src      = (const int*)d_in[1];
    const int*   dst      = (const int*)d_in[2];
    const float* w        = (const float*)d_in[3];
    const float* W1       = (const float*)d_in[4];
    const float* al1      = (const float*)d_in[5];
    const float* ar1      = (const float*)d_in[6];
    const float* W2       = (const float*)d_in[7];
    const float* al2      = (const float*)d_in[8];
    const float* ar2      = (const float*)d_in[9];
    const float* Wm       = (const float*)d_in[10];
    const float* bm       = (const float*)d_in[11];
    float* out = (float*)d_out;

    const int N = in_sizes[0] / 128;
    const int E = in_sizes[1];

    char* ws = (char*)d_ws;
    __hip_bfloat16* ftb = (__hip_bfloat16*)ws;            ws += (size_t)N * 128 * 2;
    float* x1 = (float*)ws;                               ws += (size_t)N * 128 * 4;
    float* x2 = (float*)ws;                               ws += (size_t)N * 128 * 4;
    __hip_bfloat16* el = (__hip_bfloat16*)ws;             ws += (size_t)N * 8 * 2;
    __hip_bfloat16* er = (__hip_bfloat16*)ws;             ws += (size_t)N * 8 * 2;
    int* counts = (int*)ws;                               ws += (size_t)N * 4;
    int* cursor = (int*)ws;                               ws += (size_t)N * 4;
    int* offs   = (int*)ws;                               ws += (size_t)(N + 4) * 4;
    int* bsums  = (int*)ws;                               ws += (size_t)1024 * 4;
    int2* snw   = (int2*)ws;                              ws += (size_t)E * 8;

    hipMemsetAsync(counts, 0, (size_t)N * sizeof(int), stream);
    hipMemsetAsync(cursor, 0, (size_t)N * sizeof(int), stream);

    int nb = (N + SCAN_TILE - 1) / SCAN_TILE;

    // CSR build (dst shared by both layers); (src,w) scattered into CSR order
    hist_k<<<(E + 255) / 256, 256, 0, stream>>>(dst, counts, E);
    scan_reduce_k<<<nb, 256, 0, stream>>>(counts, bsums, N);
    scan_spine_k<<<1, 1024, 0, stream>>>(bsums, nb);
    scan_final_k<<<nb, 256, 0, stream>>>(counts, bsums, offs, N, E);
    scatter_k<<<(E + 255) / 256, 256, 0, stream>>>(src, dst, w, offs, cursor, snw, E);

    int gemm_grid = (N + 63) / 64;
    int agg_grid = (N + 3) / 4;

    // ---- layer 1 ----
    gemm_fc<128, false, true><<<gemm_grid, 256, 0, stream>>>(features, nullptr, W1, nullptr, ftb, N);
    elr_k<<<(N * 8 + 255) / 256, 256, 0, stream>>>(ftb, al1, ar1, el, er, N);
    agg_k<<<agg_grid, 256, 0, stream>>>(ftb, el, er, snw, offs, x1, N);

    // ---- layer 2 ----
    gemm_fc<128, false, true><<<gemm_grid, 256, 0, stream>>>(x1, nullptr, W2, nullptr, ftb, N);
    elr_k<<<(N * 8 + 255) / 256, 256, 0, stream>>>(ftb, al2, ar2, el, er, N);
    agg_k<<<agg_grid, 256, 0, stream>>>(ftb, el, er, snw, offs, x2, N);

    // ---- final: [x1|x2] @ Wm + bm ----
    gemm_fc<256, true, false><<<gemm_grid, 256, 0, stream>>>(x1, x2, Wm, bm, out, N);
}

// Round 4
// 439.186 us; speedup vs baseline: 2.7360x; 1.2447x over previous
//
#include <hip/hip_runtime.h>
#include <hip/hip_bf16.h>

#define NEG_SLOPE 0.1f
#define SCAN_TILE 1024

typedef __attribute__((ext_vector_type(8))) short bf16x8;
typedef __attribute__((ext_vector_type(4))) float f32x4;

__device__ __forceinline__ float bf2f(unsigned u) { return __uint_as_float(u << 16); }
__device__ __forceinline__ unsigned short f2bf(float f) {
    __hip_bfloat16 h = __float2bfloat16(f);
    unsigned short r;
    __builtin_memcpy(&r, &h, 2);
    return r;
}

// ---------------- CSR build ----------------
__global__ void hist_k(const int* __restrict__ dst, int* __restrict__ counts, int E) {
    int e = blockIdx.x * blockDim.x + threadIdx.x;
    if (e < E) atomicAdd(&counts[dst[e]], 1);
}

__global__ __launch_bounds__(256) void scan_reduce_k(const int* __restrict__ counts,
                                                     int* __restrict__ blocksums, int n) {
    __shared__ int sdata[256];
    int t = threadIdx.x;
    int idx0 = blockIdx.x * SCAN_TILE + t * 4;
    int4 c = make_int4(0, 0, 0, 0);
    if (idx0 + 3 < n) c = *(const int4*)(counts + idx0);
    else {
        if (idx0     < n) c.x = counts[idx0];
        if (idx0 + 1 < n) c.y = counts[idx0 + 1];
        if (idx0 + 2 < n) c.z = counts[idx0 + 2];
        if (idx0 + 3 < n) c.w = counts[idx0 + 3];
    }
    sdata[t] = c.x + c.y + c.z + c.w;
    __syncthreads();
    for (int off = 128; off > 0; off >>= 1) {
        if (t < off) sdata[t] += sdata[t + off];
        __syncthreads();
    }
    if (t == 0) blocksums[blockIdx.x] = sdata[0];
}

__global__ __launch_bounds__(1024) void scan_spine_k(int* __restrict__ blocksums, int nb) {
    __shared__ int buf[1024];
    int t = threadIdx.x;
    int v = (t < nb) ? blocksums[t] : 0;
    buf[t] = v;
    __syncthreads();
    for (int off = 1; off < 1024; off <<= 1) {
        int u = (t >= off) ? buf[t - off] : 0;
        __syncthreads();
        buf[t] += u;
        __syncthreads();
    }
    if (t < nb) blocksums[t] = buf[t] - v;   // exclusive
}

__global__ __launch_bounds__(256) void scan_final_k(const int* __restrict__ counts,
                                                    const int* __restrict__ blocksums,
                                                    int* __restrict__ offs, int n, int E) {
    __shared__ int buf[256];
    int t = threadIdx.x;
    int idx0 = blockIdx.x * SCAN_TILE + t * 4;
    int4 c = make_int4(0, 0, 0, 0);
    if (idx0 + 3 < n) c = *(const int4*)(counts + idx0);
    else {
        if (idx0     < n) c.x = counts[idx0];
        if (idx0 + 1 < n) c.y = counts[idx0 + 1];
        if (idx0 + 2 < n) c.z = counts[idx0 + 2];
        if (idx0 + 3 < n) c.w = counts[idx0 + 3];
    }
    int s = c.x + c.y + c.z + c.w;
    buf[t] = s;
    __syncthreads();
    for (int off = 1; off < 256; off <<= 1) {
        int u = (t >= off) ? buf[t - off] : 0;
        __syncthreads();
        buf[t] += u;
        __syncthreads();
    }
    int o0 = buf[t] - s + blocksums[blockIdx.x];
    int o1 = o0 + c.x, o2 = o1 + c.y, o3 = o2 + c.z;
    if (idx0 + 3 < n) *(int4*)(offs + idx0) = make_int4(o0, o1, o2, o3);
    else {
        if (idx0     < n) offs[idx0]     = o0;
        if (idx0 + 1 < n) offs[idx0 + 1] = o1;
        if (idx0 + 2 < n) offs[idx0 + 2] = o2;
    }
    if (blockIdx.x == 0 && t == 0) offs[n] = E;
}

__global__ void scatter_k(const int* __restrict__ src, const int* __restrict__ dst,
                          const float* __restrict__ w, const int* __restrict__ offs,
                          int* __restrict__ cursor, int2* __restrict__ snw, int E) {
    int e = blockIdx.x * blockDim.x + threadIdx.x;
    if (e >= E) return;
    int d = dst[e];
    int p = atomicAdd(&cursor[d], 1);
    snw[offs[d] + p] = make_int2(src[e], __float_as_int(w[e]));
}

// ---------------- weight prep: transpose + bf16 convert ----------------
// Wt1/Wt2: [128 cols][128 k]; Wtm: [128 cols][256 k]
__global__ void prep_w_k(const float* __restrict__ W1, const float* __restrict__ W2,
                         const float* __restrict__ Wm, unsigned short* __restrict__ Wt1,
                         unsigned short* __restrict__ Wt2, unsigned short* __restrict__ Wtm) {
    int id = blockIdx.x * blockDim.x + threadIdx.x;   // 65536 threads
    if (id < 16384) {
        int k = id >> 7, c = id & 127;
        Wt1[c * 128 + k] = f2bf(W1[id]);
    } else if (id < 32768) {
        int e = id - 16384; int k = e >> 7, c = e & 127;
        Wt2[c * 128 + k] = f2bf(W2[e]);
    } else if (id < 65536) {
        int e = id - 32768;            // Wm is [256][128]
        int k = e >> 7, c = e & 127;
        Wtm[c * 256 + k] = f2bf(Wm[e]);
    }
}

// ---------------- MFMA GEMM: C[M,128] = A[M,K] @ W[K,128] (+bias) ----------------
// A supplied as one or two [M,128] panels (k-chunks). Wt is transposed bf16 [128][K].
template<int K, bool A_F32, bool BIAS, bool OUT_BF16>
__global__ __launch_bounds__(256) void gemm_mfma(const void* __restrict__ A0v,
                                                 const void* __restrict__ A1v,
                                                 const unsigned short* __restrict__ Wt,
                                                 const float* __restrict__ bias,
                                                 void* __restrict__ Cv, int M) {
    __shared__ __align__(16) unsigned short At[128 * 128];   // 32 KB, XOR-swizzled
    __shared__ __align__(16) unsigned short Bt[128 * 128];   // 32 KB, XOR-swizzled
    const int t = threadIdx.x;
    const int lane = t & 63;
    const int wv = t >> 6;            // wave 0..3
    const int m0 = blockIdx.x * 128;
    const int l15 = lane & 15;
    const int l4 = lane >> 4;         // 0..3

    f32x4 acc[2][8];
    #pragma unroll
    for (int r = 0; r < 2; ++r)
        #pragma unroll
        for (int c = 0; c < 8; ++c) acc[r][c] = (f32x4){0.f, 0.f, 0.f, 0.f};

    const int srow = t >> 4;          // 0..15
    const int scol = (t & 15) * 8;    // 0..120

    for (int k0 = 0; k0 < K; k0 += 128) {
        const int chunk = k0 >> 7;
        // ---- stage A chunk [128 rows][128 k] bf16 ----
        #pragma unroll
        for (int p = 0; p < 8; ++p) {
            int row = p * 16 + srow;
            int gm = m0 + row;
            uint4 pk = make_uint4(0, 0, 0, 0);
            if (A_F32) {
                const float* Ap = (const float*)(chunk ? A1v : A0v);
                float4 f0 = make_float4(0.f,0.f,0.f,0.f), f1 = f0;
                if (gm < M) {
                    f0 = *(const float4*)(Ap + (size_t)gm * 128 + scol);
                    f1 = *(const float4*)(Ap + (size_t)gm * 128 + scol + 4);
                }
                pk.x = f2bf(f0.x) | ((unsigned)f2bf(f0.y) << 16);
                pk.y = f2bf(f0.z) | ((unsigned)f2bf(f0.w) << 16);
                pk.z = f2bf(f1.x) | ((unsigned)f2bf(f1.y) << 16);
                pk.w = f2bf(f1.z) | ((unsigned)f2bf(f1.w) << 16);
            } else {
                const unsigned short* Ap = (const unsigned short*)(chunk ? A1v : A0v);
                if (gm < M) pk = *(const uint4*)(Ap + (size_t)gm * 128 + scol);
            }
            int byte = (row * 256 + scol * 2) ^ ((row & 7) << 4);
            *(uint4*)((char*)At + byte) = pk;
        }
        // ---- stage Wt chunk [128 cols][128 k] bf16 (straight copy) ----
        #pragma unroll
        for (int p = 0; p < 8; ++p) {
            int row = p * 16 + srow;   // col index
            uint4 pk = *(const uint4*)(Wt + (size_t)row * K + k0 + scol);
            int byte = (row * 256 + scol * 2) ^ ((row & 7) << 4);
            *(uint4*)((char*)Bt + byte) = pk;
        }
        __syncthreads();
        // ---- MFMA over this K-chunk ----
        #pragma unroll
        for (int ks = 0; ks < 4; ++ks) {
            int kb = ks * 32 + l4 * 8;
            bf16x8 af[2], bfv[8];
            #pragma unroll
            for (int r = 0; r < 2; ++r) {
                int row = wv * 32 + r * 16 + l15;
                int byte = (row * 256 + kb * 2) ^ ((row & 7) << 4);
                af[r] = *(const bf16x8*)((char*)At + byte);
            }
            #pragma unroll
            for (int c = 0; c < 8; ++c) {
                int col = c * 16 + l15;
                int byte = (col * 256 + kb * 2) ^ ((col & 7) << 4);
                bfv[c] = *(const bf16x8*)((char*)Bt + byte);
            }
            #pragma unroll
            for (int r = 0; r < 2; ++r)
                #pragma unroll
                for (int c = 0; c < 8; ++c)
                    acc[r][c] = __builtin_amdgcn_mfma_f32_16x16x32_bf16(af[r], bfv[c], acc[r][c], 0, 0, 0);
        }
        __syncthreads();
    }
    // ---- epilogue: D layout col=lane&15, row=(lane>>4)*4+reg ----
    float bb[8];
    if (BIAS) {
        #pragma unroll
        for (int c = 0; c < 8; ++c) bb[c] = bias[c * 16 + l15];
    }
    #pragma unroll
    for (int r = 0; r < 2; ++r) {
        #pragma unroll
        for (int q = 0; q < 4; ++q) {
            int row = m0 + wv * 32 + r * 16 + l4 * 4 + q;
            if (row < M) {
                #pragma unroll
                for (int c = 0; c < 8; ++c) {
                    int col = c * 16 + l15;
                    float v = acc[r][c][q];
                    if (BIAS) v += bb[c];
                    if (OUT_BF16) ((unsigned short*)Cv)[(size_t)row * 128 + col] = f2bf(v);
                    else          ((float*)Cv)[(size_t)row * 128 + col] = v;
                }
            }
        }
    }
}

// ---------------- el/er: dot(ft[n,h,:], al[h,:]) (bf16 in, bf16 out) ----------------
__global__ void elr_k(const __hip_bfloat16* __restrict__ ft, const float* __restrict__ al,
                      const float* __restrict__ ar, __hip_bfloat16* __restrict__ el,
                      __hip_bfloat16* __restrict__ er, int n) {
    int idx = blockIdx.x * blockDim.x + threadIdx.x;
    if (idx >= n * 8) return;
    int node = idx >> 3, h = idx & 7;
    const __hip_bfloat16* f = ft + (size_t)node * 128 + h * 16;
    uint4 a = *(const uint4*)f;
    uint4 b = *(const uint4*)(f + 8);
    float fv[16];
    fv[0]  = bf2f(a.x & 0xffff); fv[1]  = bf2f(a.x >> 16);
    fv[2]  = bf2f(a.y & 0xffff); fv[3]  = bf2f(a.y >> 16);
    fv[4]  = bf2f(a.z & 0xffff); fv[5]  = bf2f(a.z >> 16);
    fv[6]  = bf2f(a.w & 0xffff); fv[7]  = bf2f(a.w >> 16);
    fv[8]  = bf2f(b.x & 0xffff); fv[9]  = bf2f(b.x >> 16);
    fv[10] = bf2f(b.y & 0xffff); fv[11] = bf2f(b.y >> 16);
    fv[12] = bf2f(b.z & 0xffff); fv[13] = bf2f(b.z >> 16);
    fv[14] = bf2f(b.w & 0xffff); fv[15] = bf2f(b.w >> 16);
    float e1 = 0.f, e2 = 0.f;
    #pragma unroll
    for (int d = 0; d < 16; ++d) { e1 += fv[d] * al[h * 16 + d]; e2 += fv[d] * ar[h * 16 + d]; }
    unsigned short r1 = f2bf(e1), r2 = f2bf(e2);
    __builtin_memcpy(&el[idx], &r1, 2);
    __builtin_memcpy(&er[idx], &r2, 2);
}

// ---------------- aggregation: one wave per dst node, bf16 output ----------------
__global__ __launch_bounds__(256) void agg_k(const __hip_bfloat16* __restrict__ ftb,
                                             const __hip_bfloat16* __restrict__ el,
                                             const __hip_bfloat16* __restrict__ er,
                                             const int2* __restrict__ snw,
                                             const int* __restrict__ offs,
                                             unsigned short* __restrict__ out, int n) {
    __shared__ float pbuf[4][64][9];
    __shared__ int   snbuf[4][64];
    int wid = threadIdx.x >> 6;
    int node = blockIdx.x * 4 + wid;
    if (node >= n) return;
    int lane = threadIdx.x & 63;
    int g8 = lane >> 3;
    int beg = offs[node], end = offs[node + 1];
    int deg = end - beg;

    float erv[8];
    {
        uint4 u = *(const uint4*)(er + (size_t)node * 8);
        erv[0] = bf2f(u.x & 0xffff); erv[1] = bf2f(u.x >> 16);
        erv[2] = bf2f(u.y & 0xffff); erv[3] = bf2f(u.y >> 16);
        erv[4] = bf2f(u.z & 0xffff); erv[5] = bf2f(u.z >> 16);
        erv[6] = bf2f(u.w & 0xffff); erv[7] = bf2f(u.w >> 16);
    }

    float spart[8];
    #pragma unroll
    for (int h = 0; h < 8; ++h) spart[h] = 0.f;
    float acc0 = 0.f, acc1 = 0.f;

    for (int c0 = 0; c0 < deg; c0 += 64) {
        int cnt = min(64, deg - c0);
        bool act = lane < cnt;
        int sn = 0; float wv = 0.f;
        float elv[8];
        #pragma unroll
        for (int h = 0; h < 8; ++h) elv[h] = 0.f;
        if (act) {
            int2 p2 = snw[beg + c0 + lane];
            sn = p2.x; wv = __int_as_float(p2.y);
            uint4 u = *(const uint4*)(el + (size_t)sn * 8);
            elv[0] = bf2f(u.x & 0xffff); elv[1] = bf2f(u.x >> 16);
            elv[2] = bf2f(u.y & 0xffff); elv[3] = bf2f(u.y >> 16);
            elv[4] = bf2f(u.z & 0xffff); elv[5] = bf2f(u.z >> 16);
            elv[6] = bf2f(u.w & 0xffff); elv[7] = bf2f(u.w >> 16);
        }
        float p[8];
        #pragma unroll
        for (int h = 0; h < 8; ++h) {
            float tt = elv[h] + erv[h];
            tt = tt > 0.f ? tt : NEG_SLOPE * tt;
            tt *= wv;
            p[h] = act ? __expf(tt) : 0.f;
            spart[h] += p[h];
        }
        snbuf[wid][lane] = sn;
        #pragma unroll
        for (int h = 0; h < 8; ++h) pbuf[wid][lane][h] = p[h];
        __builtin_amdgcn_wave_barrier();
        asm volatile("s_waitcnt lgkmcnt(0)" ::: "memory");
        __builtin_amdgcn_wave_barrier();

        #pragma unroll 4
        for (int j = 0; j < cnt; ++j) {
            int sj = snbuf[wid][j];
            float a = pbuf[wid][j][g8];
            unsigned u = *(const unsigned*)(ftb + (size_t)sj * 128 + lane * 2);
            acc0 += a * bf2f(u & 0xffff);
            acc1 += a * bf2f(u >> 16);
        }
        __builtin_amdgcn_wave_barrier();
    }

    #pragma unroll
    for (int h = 0; h < 8; ++h) {
        float tt = spart[h];
        tt += __shfl_xor(tt, 1);  tt += __shfl_xor(tt, 2);  tt += __shfl_xor(tt, 4);
        tt += __shfl_xor(tt, 8);  tt += __shfl_xor(tt, 16); tt += __shfl_xor(tt, 32);
        spart[h] = tt;
    }
    float sg = (g8 & 4) ? ((g8 & 2) ? ((g8 & 1) ? spart[7] : spart[6])
                                    : ((g8 & 1) ? spart[5] : spart[4]))
                        : ((g8 & 2) ? ((g8 & 1) ? spart[3] : spart[2])
                                    : ((g8 & 1) ? spart[1] : spart[0]));
    float sinv = sg > 0.f ? 1.f / sg : 0.f;
    float o0 = fmaxf(acc0 * sinv, 0.f);
    float o1 = fmaxf(acc1 * sinv, 0.f);
    unsigned pk = f2bf(o0) | ((unsigned)f2bf(o1) << 16);
    *(unsigned*)(out + (size_t)node * 128 + lane * 2) = pk;
}

extern "C" void kernel_launch(void* const* d_in, const int* in_sizes, int n_in,
                              void* d_out, int out_size, void* d_ws, size_t ws_size,
                              hipStream_t stream) {
    const float* features = (const float*)d_in[0];
    const int*   src      = (const int*)d_in[1];
    const int*   dst      = (const int*)d_in[2];
    const float* w        = (const float*)d_in[3];
    const float* W1       = (const float*)d_in[4];
    const float* al1      = (const float*)d_in[5];
    const float* ar1      = (const float*)d_in[6];
    const float* W2       = (const float*)d_in[7];
    const float* al2      = (const float*)d_in[8];
    const float* ar2      = (const float*)d_in[9];
    const float* Wm       = (const float*)d_in[10];
    const float* bm       = (const float*)d_in[11];
    float* out = (float*)d_out;

    const int N = in_sizes[0] / 128;
    const int E = in_sizes[1];

    char* ws = (char*)d_ws;
    unsigned short* ftb = (unsigned short*)ws;            ws += (size_t)N * 128 * 2;
    unsigned short* x1b = (unsigned short*)ws;            ws += (size_t)N * 128 * 2;
    unsigned short* x2b = (unsigned short*)ws;            ws += (size_t)N * 128 * 2;
    unsigned short* el  = (unsigned short*)ws;            ws += (size_t)N * 8 * 2;
    unsigned short* er  = (unsigned short*)ws;            ws += (size_t)N * 8 * 2;
    unsigned short* Wt1 = (unsigned short*)ws;            ws += (size_t)128 * 128 * 2;
    unsigned short* Wt2 = (unsigned short*)ws;            ws += (size_t)128 * 128 * 2;
    unsigned short* Wtm = (unsigned short*)ws;            ws += (size_t)128 * 256 * 2;
    int* counts = (int*)ws;                               ws += (size_t)N * 4;
    int* cursor = (int*)ws;                               ws += (size_t)N * 4;
    int* offs   = (int*)ws;                               ws += (size_t)(N + 4) * 4;
    int* bsums  = (int*)ws;                               ws += (size_t)1024 * 4;
    int2* snw   = (int2*)ws;                              ws += (size_t)E * 8;

    hipMemsetAsync(counts, 0, (size_t)N * sizeof(int), stream);
    hipMemsetAsync(cursor, 0, (size_t)N * sizeof(int), stream);

    int nb = (N + SCAN_TILE - 1) / SCAN_TILE;

    // weight prep (independent; cheap)
    prep_w_k<<<256, 256, 0, stream>>>(W1, W2, Wm, Wt1, Wt2, Wtm);

    // CSR build
    hist_k<<<(E + 255) / 256, 256, 0, stream>>>(dst, counts, E);
    scan_reduce_k<<<nb, 256, 0, stream>>>(counts, bsums, N);
    scan_spine_k<<<1, 1024, 0, stream>>>(bsums, nb);
    scan_final_k<<<nb, 256, 0, stream>>>(counts, bsums, offs, N, E);
    scatter_k<<<(E + 255) / 256, 256, 0, stream>>>(src, dst, w, offs, cursor, snw, E);

    int gemm_grid = (N + 127) / 128;
    int agg_grid = (N + 3) / 4;

    // ---- layer 1 ----
    gemm_mfma<128, true, false, true><<<gemm_grid, 256, 0, stream>>>(features, nullptr, Wt1, nullptr, ftb, N);
    elr_k<<<(N * 8 + 255) / 256, 256, 0, stream>>>((const __hip_bfloat16*)ftb, al1, ar1,
                                                   (__hip_bfloat16*)el, (__hip_bfloat16*)er, N);
    agg_k<<<agg_grid, 256, 0, stream>>>((const __hip_bfloat16*)ftb, (const __hip_bfloat16*)el,
                                        (const __hip_bfloat16*)er, snw, offs, x1b, N);

    // ---- layer 2 ----
    gemm_mfma<128, false, false, true><<<gemm_grid, 256, 0, stream>>>(x1b, nullptr, Wt2, nullptr, ftb, N);
    elr_k<<<(N * 8 + 255) / 256, 256, 0, stream>>>((const __hip_bfloat16*)ftb, al2, ar2,
                                                   (__hip_bfloat16*)el, (__hip_bfloat16*)er, N);
    agg_k<<<agg_grid, 256, 0, stream>>>((const __hip_bfloat16*)ftb, (const __hip_bfloat16*)el,
                                        (const __hip_bfloat16*)er, snw, offs, x2b, N);

    // ---- final: [x1|x2] @ Wm + bm (f32 out) ----
    gemm_mfma<256, false, true, false><<<gemm_grid, 256, 0, stream>>>(x1b, x2b, Wtm, bm, out, N);
}

// Round 5
// 314.208 us; speedup vs baseline: 3.8243x; 1.3978x over previous
//
#include <hip/hip_runtime.h>
#include <hip/hip_bf16.h>

#define NEG_SLOPE 0.1f
#define EPB 4096        // edges per block for binning passes
#define BINSH 9         // 512 nodes per bin

typedef __attribute__((ext_vector_type(8))) short bf16x8;
typedef __attribute__((ext_vector_type(4))) float f32x4;

__device__ __forceinline__ float bf2f(unsigned u) { return __uint_as_float(u << 16); }
__device__ __forceinline__ unsigned short f2bf(float f) {
    __hip_bfloat16 h = __float2bfloat16(f);
    unsigned short r;
    __builtin_memcpy(&r, &h, 2);
    return r;
}

// ---------------- CSR build, two-level binned (no global random atomics) ----------------
// A: coarse bin histogram (bin = dst>>9)
__global__ __launch_bounds__(256) void binhist_k(const int* __restrict__ dst,
                                                 int* __restrict__ bin_counts, int E) {
    __shared__ int cnt[256];
    int t = threadIdx.x;
    cnt[t] = 0;
    __syncthreads();
    int base = blockIdx.x * EPB;
    if (base + EPB <= E) {
        const int4* d4 = (const int4*)(dst + base);
        #pragma unroll
        for (int i = 0; i < 4; ++i) {
            int4 v = d4[i * 256 + t];
            atomicAdd(&cnt[v.x >> BINSH], 1);
            atomicAdd(&cnt[v.y >> BINSH], 1);
            atomicAdd(&cnt[v.z >> BINSH], 1);
            atomicAdd(&cnt[v.w >> BINSH], 1);
        }
    } else {
        for (int i = 0; i < 4; ++i) {
            int j0 = base + (i * 256 + t) * 4;
            #pragma unroll
            for (int c = 0; c < 4; ++c)
                if (j0 + c < E) atomicAdd(&cnt[dst[j0 + c] >> BINSH], 1);
        }
    }
    __syncthreads();
    if (cnt[t]) atomicAdd(&bin_counts[t], cnt[t]);
}

// B: single-block scan of 256 bin counts -> binoffs[257] and gcur (cursors)
__global__ __launch_bounds__(256) void scan256_k(const int* __restrict__ bin_counts,
                                                 int* __restrict__ binoffs,
                                                 int* __restrict__ gcur, int nbins) {
    __shared__ int sbuf[256];
    int t = threadIdx.x;
    int c = (t < nbins) ? bin_counts[t] : 0;
    sbuf[t] = c;
    __syncthreads();
    for (int off = 1; off < 256; off <<= 1) {
        int u = (t >= off) ? sbuf[t - off] : 0;
        __syncthreads();
        sbuf[t] += u;
        __syncthreads();
    }
    int ex = sbuf[t] - c;          // exclusive
    binoffs[t] = ex;
    if (t == 255) binoffs[256] = ex + c;
    gcur[t] = ex;
}

// C: scatter edges into coarse-bin regions (chunked appends, full-line writes)
__global__ __launch_bounds__(256) void binify_k(const int* __restrict__ src,
                                                const int* __restrict__ dst,
                                                const float* __restrict__ w,
                                                int* __restrict__ gcur,
                                                int4* __restrict__ tmp, int E) {
    __shared__ int cnt[256];
    __shared__ int basearr[256];
    int t = threadIdx.x;
    cnt[t] = 0;
    __syncthreads();
    int base = blockIdx.x * EPB;
    int es[16], ed[16], ew[16];
    bool va[16];
    if (base + EPB <= E) {
        const int4* s4 = (const int4*)(src + base);
        const int4* d4 = (const int4*)(dst + base);
        const int4* w4 = (const int4*)(w + base);
        #pragma unroll
        for (int i = 0; i < 4; ++i) {
            int slot = i * 256 + t;
            int4 sv = s4[slot]; int4 dv = d4[slot]; int4 wv = w4[slot];
            es[i*4+0]=sv.x; es[i*4+1]=sv.y; es[i*4+2]=sv.z; es[i*4+3]=sv.w;
            ed[i*4+0]=dv.x; ed[i*4+1]=dv.y; ed[i*4+2]=dv.z; ed[i*4+3]=dv.w;
            ew[i*4+0]=wv.x; ew[i*4+1]=wv.y; ew[i*4+2]=wv.z; ew[i*4+3]=wv.w;
            va[i*4+0]=va[i*4+1]=va[i*4+2]=va[i*4+3]=true;
        }
    } else {
        #pragma unroll
        for (int i = 0; i < 4; ++i) {
            #pragma unroll
            for (int c = 0; c < 4; ++c) {
                int j = base + (i * 256 + t) * 4 + c;
                bool v = j < E;
                va[i*4+c] = v;
                es[i*4+c] = v ? src[j] : 0;
                ed[i*4+c] = v ? dst[j] : 0;
                ew[i*4+c] = v ? __float_as_int(w[j]) : 0;
            }
        }
    }
    #pragma unroll
    for (int i = 0; i < 16; ++i)
        if (va[i]) atomicAdd(&cnt[ed[i] >> BINSH], 1);
    __syncthreads();
    int c = cnt[t];
    basearr[t] = c ? atomicAdd(&gcur[t], c) : 0;
    __syncthreads();
    cnt[t] = 0;
    __syncthreads();
    #pragma unroll
    for (int i = 0; i < 16; ++i) {
        if (va[i]) {
            int b = ed[i] >> BINSH;
            int pos = atomicAdd(&cnt[b], 1);
            tmp[basearr[b] + pos] = make_int4(es[i], ew[i], ed[i], 0);
        }
    }
}

// D: per-bin finalize: node offsets (LDS scan) + place (src,w) into snw
__global__ __launch_bounds__(256) void binfin_k(const int4* __restrict__ tmp,
                                                const int* __restrict__ binoffs,
                                                int* __restrict__ offs,
                                                int2* __restrict__ snw, int N, int E) {
    __shared__ int ncnt[512];
    __shared__ int noff[512];
    __shared__ int sbuf[256];
    int b = blockIdx.x, t = threadIdx.x;
    int lo = b << BINSH;
    int hi = min(lo + 512, N);
    int ebeg = binoffs[b], eend = binoffs[b + 1];
    ncnt[t] = 0; ncnt[t + 256] = 0;
    __syncthreads();
    for (int j = ebeg + t; j < eend; j += 256)
        atomicAdd(&ncnt[tmp[j].z - lo], 1);
    __syncthreads();
    int a0 = ncnt[2 * t], a1 = ncnt[2 * t + 1];
    sbuf[t] = a0 + a1;
    __syncthreads();
    for (int off = 1; off < 256; off <<= 1) {
        int u = (t >= off) ? sbuf[t - off] : 0;
        __syncthreads();
        sbuf[t] += u;
        __syncthreads();
    }
    int ex = sbuf[t] - (a0 + a1);
    noff[2 * t] = ex;
    noff[2 * t + 1] = ex + a0;
    if (lo + 2 * t     < hi) offs[lo + 2 * t]     = ebeg + ex;
    if (lo + 2 * t + 1 < hi) offs[lo + 2 * t + 1] = ebeg + ex + a0;
    if (b == 0 && t == 0) offs[N] = E;
    ncnt[t] = 0; ncnt[t + 256] = 0;
    __syncthreads();
    for (int j = ebeg + t; j < eend; j += 256) {
        int4 e = tmp[j];
        int idx = e.z - lo;
        int pos = atomicAdd(&ncnt[idx], 1);
        snw[ebeg + noff[idx] + pos] = make_int2(e.x, e.y);
    }
}

// ---------------- weight prep: transpose + bf16 convert ----------------
__global__ void prep_w_k(const float* __restrict__ W1, const float* __restrict__ W2,
                         const float* __restrict__ Wm, unsigned short* __restrict__ Wt1,
                         unsigned short* __restrict__ Wt2, unsigned short* __restrict__ Wtm) {
    int id = blockIdx.x * blockDim.x + threadIdx.x;
    if (id < 16384) {
        int k = id >> 7, c = id & 127;
        Wt1[c * 128 + k] = f2bf(W1[id]);
    } else if (id < 32768) {
        int e = id - 16384; int k = e >> 7, c = e & 127;
        Wt2[c * 128 + k] = f2bf(W2[e]);
    } else if (id < 65536) {
        int e = id - 32768;            // Wm is [256][128]
        int k = e >> 7, c = e & 127;
        Wtm[c * 256 + k] = f2bf(Wm[e]);
    }
}

// ---------------- MFMA GEMM: C[M,128] = A[M,K] @ W[K,128] (+bias) ----------------
template<int K, bool A_F32, bool BIAS, bool OUT_BF16>
__global__ __launch_bounds__(256) void gemm_mfma(const void* __restrict__ A0v,
                                                 const void* __restrict__ A1v,
                                                 const unsigned short* __restrict__ Wt,
                                                 const float* __restrict__ bias,
                                                 void* __restrict__ Cv, int M) {
    __shared__ __align__(16) unsigned short At[128 * 128];   // 32 KB, XOR-swizzled
    __shared__ __align__(16) unsigned short Bt[128 * 128];   // 32 KB, XOR-swizzled
    const int t = threadIdx.x;
    const int lane = t & 63;
    const int wv = t >> 6;
    const int m0 = blockIdx.x * 128;
    const int l15 = lane & 15;
    const int l4 = lane >> 4;

    f32x4 acc[2][8];
    #pragma unroll
    for (int r = 0; r < 2; ++r)
        #pragma unroll
        for (int c = 0; c < 8; ++c) acc[r][c] = (f32x4){0.f, 0.f, 0.f, 0.f};

    const int srow = t >> 4;
    const int scol = (t & 15) * 8;

    for (int k0 = 0; k0 < K; k0 += 128) {
        const int chunk = k0 >> 7;
        #pragma unroll
        for (int p = 0; p < 8; ++p) {
            int row = p * 16 + srow;
            int gm = m0 + row;
            uint4 pk = make_uint4(0, 0, 0, 0);
            if (A_F32) {
                const float* Ap = (const float*)(chunk ? A1v : A0v);
                float4 f0 = make_float4(0.f,0.f,0.f,0.f), f1 = f0;
                if (gm < M) {
                    f0 = *(const float4*)(Ap + (size_t)gm * 128 + scol);
                    f1 = *(const float4*)(Ap + (size_t)gm * 128 + scol + 4);
                }
                pk.x = f2bf(f0.x) | ((unsigned)f2bf(f0.y) << 16);
                pk.y = f2bf(f0.z) | ((unsigned)f2bf(f0.w) << 16);
                pk.z = f2bf(f1.x) | ((unsigned)f2bf(f1.y) << 16);
                pk.w = f2bf(f1.z) | ((unsigned)f2bf(f1.w) << 16);
            } else {
                const unsigned short* Ap = (const unsigned short*)(chunk ? A1v : A0v);
                if (gm < M) pk = *(const uint4*)(Ap + (size_t)gm * 128 + scol);
            }
            int byte = (row * 256 + scol * 2) ^ ((row & 7) << 4);
            *(uint4*)((char*)At + byte) = pk;
        }
        #pragma unroll
        for (int p = 0; p < 8; ++p) {
            int row = p * 16 + srow;
            uint4 pk = *(const uint4*)(Wt + (size_t)row * K + k0 + scol);
            int byte = (row * 256 + scol * 2) ^ ((row & 7) << 4);
            *(uint4*)((char*)Bt + byte) = pk;
        }
        __syncthreads();
        #pragma unroll
        for (int ks = 0; ks < 4; ++ks) {
            int kb = ks * 32 + l4 * 8;
            bf16x8 af[2], bfv[8];
            #pragma unroll
            for (int r = 0; r < 2; ++r) {
                int row = wv * 32 + r * 16 + l15;
                int byte = (row * 256 + kb * 2) ^ ((row & 7) << 4);
                af[r] = *(const bf16x8*)((char*)At + byte);
            }
            #pragma unroll
            for (int c = 0; c < 8; ++c) {
                int col = c * 16 + l15;
                int byte = (col * 256 + kb * 2) ^ ((col & 7) << 4);
                bfv[c] = *(const bf16x8*)((char*)Bt + byte);
            }
            #pragma unroll
            for (int r = 0; r < 2; ++r)
                #pragma unroll
                for (int c = 0; c < 8; ++c)
                    acc[r][c] = __builtin_amdgcn_mfma_f32_16x16x32_bf16(af[r], bfv[c], acc[r][c], 0, 0, 0);
        }
        __syncthreads();
    }
    float bb[8];
    if (BIAS) {
        #pragma unroll
        for (int c = 0; c < 8; ++c) bb[c] = bias[c * 16 + l15];
    }
    #pragma unroll
    for (int r = 0; r < 2; ++r) {
        #pragma unroll
        for (int q = 0; q < 4; ++q) {
            int row = m0 + wv * 32 + r * 16 + l4 * 4 + q;
            if (row < M) {
                #pragma unroll
                for (int c = 0; c < 8; ++c) {
                    int col = c * 16 + l15;
                    float v = acc[r][c][q];
                    if (BIAS) v += bb[c];
                    if (OUT_BF16) ((unsigned short*)Cv)[(size_t)row * 128 + col] = f2bf(v);
                    else          ((float*)Cv)[(size_t)row * 128 + col] = v;
                }
            }
        }
    }
}

// ---------------- el/er ----------------
__global__ void elr_k(const __hip_bfloat16* __restrict__ ft, const float* __restrict__ al,
                      const float* __restrict__ ar, __hip_bfloat16* __restrict__ el,
                      __hip_bfloat16* __restrict__ er, int n) {
    int idx = blockIdx.x * blockDim.x + threadIdx.x;
    if (idx >= n * 8) return;
    int node = idx >> 3, h = idx & 7;
    const __hip_bfloat16* f = ft + (size_t)node * 128 + h * 16;
    uint4 a = *(const uint4*)f;
    uint4 b = *(const uint4*)(f + 8);
    float fv[16];
    fv[0]  = bf2f(a.x & 0xffff); fv[1]  = bf2f(a.x >> 16);
    fv[2]  = bf2f(a.y & 0xffff); fv[3]  = bf2f(a.y >> 16);
    fv[4]  = bf2f(a.z & 0xffff); fv[5]  = bf2f(a.z >> 16);
    fv[6]  = bf2f(a.w & 0xffff); fv[7]  = bf2f(a.w >> 16);
    fv[8]  = bf2f(b.x & 0xffff); fv[9]  = bf2f(b.x >> 16);
    fv[10] = bf2f(b.y & 0xffff); fv[11] = bf2f(b.y >> 16);
    fv[12] = bf2f(b.z & 0xffff); fv[13] = bf2f(b.z >> 16);
    fv[14] = bf2f(b.w & 0xffff); fv[15] = bf2f(b.w >> 16);
    float e1 = 0.f, e2 = 0.f;
    #pragma unroll
    for (int d = 0; d < 16; ++d) { e1 += fv[d] * al[h * 16 + d]; e2 += fv[d] * ar[h * 16 + d]; }
    unsigned short r1 = f2bf(e1), r2 = f2bf(e2);
    __builtin_memcpy(&el[idx], &r1, 2);
    __builtin_memcpy(&er[idx], &r2, 2);
}

// ---------------- aggregation: one wave per dst node, bf16 output ----------------
__global__ __launch_bounds__(256) void agg_k(const __hip_bfloat16* __restrict__ ftb,
                                             const __hip_bfloat16* __restrict__ el,
                                             const __hip_bfloat16* __restrict__ er,
                                             const int2* __restrict__ snw,
                                             const int* __restrict__ offs,
                                             unsigned short* __restrict__ out, int n) {
    __shared__ float pbuf[4][64][9];
    __shared__ int   snbuf[4][64];
    int wid = threadIdx.x >> 6;
    int node = blockIdx.x * 4 + wid;
    if (node >= n) return;
    int lane = threadIdx.x & 63;
    int g8 = lane >> 3;
    int beg = offs[node], end = offs[node + 1];
    int deg = end - beg;

    float erv[8];
    {
        uint4 u = *(const uint4*)(er + (size_t)node * 8);
        erv[0] = bf2f(u.x & 0xffff); erv[1] = bf2f(u.x >> 16);
        erv[2] = bf2f(u.y & 0xffff); erv[3] = bf2f(u.y >> 16);
        erv[4] = bf2f(u.z & 0xffff); erv[5] = bf2f(u.z >> 16);
        erv[6] = bf2f(u.w & 0xffff); erv[7] = bf2f(u.w >> 16);
    }

    float spart[8];
    #pragma unroll
    for (int h = 0; h < 8; ++h) spart[h] = 0.f;
    float acc0 = 0.f, acc1 = 0.f;

    for (int c0 = 0; c0 < deg; c0 += 64) {
        int cnt = min(64, deg - c0);
        bool act = lane < cnt;
        int sn = 0; float wv = 0.f;
        float elv[8];
        #pragma unroll
        for (int h = 0; h < 8; ++h) elv[h] = 0.f;
        if (act) {
            int2 p2 = snw[beg + c0 + lane];
            sn = p2.x; wv = __int_as_float(p2.y);
            uint4 u = *(const uint4*)(el + (size_t)sn * 8);
            elv[0] = bf2f(u.x & 0xffff); elv[1] = bf2f(u.x >> 16);
            elv[2] = bf2f(u.y & 0xffff); elv[3] = bf2f(u.y >> 16);
            elv[4] = bf2f(u.z & 0xffff); elv[5] = bf2f(u.z >> 16);
            elv[6] = bf2f(u.w & 0xffff); elv[7] = bf2f(u.w >> 16);
        }
        float p[8];
        #pragma unroll
        for (int h = 0; h < 8; ++h) {
            float tt = elv[h] + erv[h];
            tt = tt > 0.f ? tt : NEG_SLOPE * tt;
            tt *= wv;
            p[h] = act ? __expf(tt) : 0.f;
            spart[h] += p[h];
        }
        snbuf[wid][lane] = sn;
        #pragma unroll
        for (int h = 0; h < 8; ++h) pbuf[wid][lane][h] = p[h];
        __builtin_amdgcn_wave_barrier();
        asm volatile("s_waitcnt lgkmcnt(0)" ::: "memory");
        __builtin_amdgcn_wave_barrier();

        #pragma unroll 4
        for (int j = 0; j < cnt; ++j) {
            int sj = snbuf[wid][j];
            float a = pbuf[wid][j][g8];
            unsigned u = *(const unsigned*)(ftb + (size_t)sj * 128 + lane * 2);
            acc0 += a * bf2f(u & 0xffff);
            acc1 += a * bf2f(u >> 16);
        }
        __builtin_amdgcn_wave_barrier();
    }

    #pragma unroll
    for (int h = 0; h < 8; ++h) {
        float tt = spart[h];
        tt += __shfl_xor(tt, 1);  tt += __shfl_xor(tt, 2);  tt += __shfl_xor(tt, 4);
        tt += __shfl_xor(tt, 8);  tt += __shfl_xor(tt, 16); tt += __shfl_xor(tt, 32);
        spart[h] = tt;
    }
    float sg = (g8 & 4) ? ((g8 & 2) ? ((g8 & 1) ? spart[7] : spart[6])
                                    : ((g8 & 1) ? spart[5] : spart[4]))
                        : ((g8 & 2) ? ((g8 & 1) ? spart[3] : spart[2])
                                    : ((g8 & 1) ? spart[1] : spart[0]));
    float sinv = sg > 0.f ? 1.f / sg : 0.f;
    float o0 = fmaxf(acc0 * sinv, 0.f);
    float o1 = fmaxf(acc1 * sinv, 0.f);
    unsigned pk = f2bf(o0) | ((unsigned)f2bf(o1) << 16);
    *(unsigned*)(out + (size_t)node * 128 + lane * 2) = pk;
}

extern "C" void kernel_launch(void* const* d_in, const int* in_sizes, int n_in,
                              void* d_out, int out_size, void* d_ws, size_t ws_size,
                              hipStream_t stream) {
    const float* features = (const float*)d_in[0];
    const int*   src      = (const int*)d_in[1];
    const int*   dst      = (const int*)d_in[2];
    const float* w        = (const float*)d_in[3];
    const float* W1       = (const float*)d_in[4];
    const float* al1      = (const float*)d_in[5];
    const float* ar1      = (const float*)d_in[6];
    const float* W2       = (const float*)d_in[7];
    const float* al2      = (const float*)d_in[8];
    const float* ar2      = (const float*)d_in[9];
    const float* Wm       = (const float*)d_in[10];
    const float* bm       = (const float*)d_in[11];
    float* out = (float*)d_out;

    const int N = in_sizes[0] / 128;
    const int E = in_sizes[1];

    char* ws = (char*)d_ws;
    unsigned short* ftb = (unsigned short*)ws;            ws += (size_t)N * 128 * 2;
    unsigned short* x1b = (unsigned short*)ws;            ws += (size_t)N * 128 * 2;
    unsigned short* x2b = (unsigned short*)ws;            ws += (size_t)N * 128 * 2;
    unsigned short* el  = (unsigned short*)ws;            ws += (size_t)N * 8 * 2;
    unsigned short* er  = (unsigned short*)ws;            ws += (size_t)N * 8 * 2;
    unsigned short* Wt1 = (unsigned short*)ws;            ws += (size_t)128 * 128 * 2;
    unsigned short* Wt2 = (unsigned short*)ws;            ws += (size_t)128 * 128 * 2;
    unsigned short* Wtm = (unsigned short*)ws;            ws += (size_t)128 * 256 * 2;
    int* offs      = (int*)ws;                            ws += (size_t)(N + 4) * 4;
    int* bin_counts= (int*)ws;                            ws += 256 * 4;
    int* binoffs   = (int*)ws;                            ws += 260 * 4;
    int* gcur      = (int*)ws;                            ws += 256 * 4;
    int2* snw      = (int2*)ws;                           ws += (size_t)E * 8;
    // tmp aliases x1b/x2b (used only during CSR build, before layer 1 writes x1b)
    int4* tmp = (int4*)x1b;

    hipMemsetAsync(bin_counts, 0, 256 * sizeof(int), stream);

    const int nbins = (N + 511) >> BINSH;
    const int nblk_e = (E + EPB - 1) / EPB;

    // weight prep (independent; cheap)
    prep_w_k<<<256, 256, 0, stream>>>(W1, W2, Wm, Wt1, Wt2, Wtm);

    // CSR build (binned)
    binhist_k<<<nblk_e, 256, 0, stream>>>(dst, bin_counts, E);
    scan256_k<<<1, 256, 0, stream>>>(bin_counts, binoffs, gcur, nbins);
    binify_k<<<nblk_e, 256, 0, stream>>>(src, dst, w, gcur, tmp, E);
    binfin_k<<<nbins, 256, 0, stream>>>(tmp, binoffs, offs, snw, N, E);

    int gemm_grid = (N + 127) / 128;
    int agg_grid = (N + 3) / 4;

    // ---- layer 1 ----
    gemm_mfma<128, true, false, true><<<gemm_grid, 256, 0, stream>>>(features, nullptr, Wt1, nullptr, ftb, N);
    elr_k<<<(N * 8 + 255) / 256, 256, 0, stream>>>((const __hip_bfloat16*)ftb, al1, ar1,
                                                   (__hip_bfloat16*)el, (__hip_bfloat16*)er, N);
    agg_k<<<agg_grid, 256, 0, stream>>>((const __hip_bfloat16*)ftb, (const __hip_bfloat16*)el,
                                        (const __hip_bfloat16*)er, snw, offs, x1b, N);

    // ---- layer 2 ----
    gemm_mfma<128, false, false, true><<<gemm_grid, 256, 0, stream>>>(x1b, nullptr, Wt2, nullptr, ftb, N);
    elr_k<<<(N * 8 + 255) / 256, 256, 0, stream>>>((const __hip_bfloat16*)ftb, al2, ar2,
                                                   (__hip_bfloat16*)el, (__hip_bfloat16*)er, N);
    agg_k<<<agg_grid, 256, 0, stream>>>((const __hip_bfloat16*)ftb, (const __hip_bfloat16*)el,
                                        (const __hip_bfloat16*)er, snw, offs, x2b, N);

    // ---- final: [x1|x2] @ Wm + bm (f32 out) ----
    gemm_mfma<256, false, true, false><<<gemm_grid, 256, 0, stream>>>(x1b, x2b, Wtm, bm, out, N);
}

// Round 6
// 295.279 us; speedup vs baseline: 4.0695x; 1.0641x over previous
//
#include <hip/hip_runtime.h>
#include <hip/hip_bf16.h>

#define NEG_SLOPE 0.1f
#define EPB 4096        // edges per block for binning passes
#define BINSH 9         // 512 nodes per bin

typedef __attribute__((ext_vector_type(8))) short bf16x8;
typedef __attribute__((ext_vector_type(4))) float f32x4;

__device__ __forceinline__ float bf2f(unsigned u) { return __uint_as_float(u << 16); }
__device__ __forceinline__ unsigned short f2bf(float f) {
    __hip_bfloat16 h = __float2bfloat16(f);
    unsigned short r;
    __builtin_memcpy(&r, &h, 2);
    return r;
}

// ---------------- CSR build, two-level binned (no global random atomics) ----------------
__global__ __launch_bounds__(256) void binhist_k(const int* __restrict__ dst,
                                                 int* __restrict__ bin_counts, int E) {
    __shared__ int cnt[256];
    int t = threadIdx.x;
    cnt[t] = 0;
    __syncthreads();
    int base = blockIdx.x * EPB;
    if (base + EPB <= E) {
        const int4* d4 = (const int4*)(dst + base);
        #pragma unroll
        for (int i = 0; i < 4; ++i) {
            int4 v = d4[i * 256 + t];
            atomicAdd(&cnt[v.x >> BINSH], 1);
            atomicAdd(&cnt[v.y >> BINSH], 1);
            atomicAdd(&cnt[v.z >> BINSH], 1);
            atomicAdd(&cnt[v.w >> BINSH], 1);
        }
    } else {
        for (int i = 0; i < 4; ++i) {
            int j0 = base + (i * 256 + t) * 4;
            #pragma unroll
            for (int c = 0; c < 4; ++c)
                if (j0 + c < E) atomicAdd(&cnt[dst[j0 + c] >> BINSH], 1);
        }
    }
    __syncthreads();
    if (cnt[t]) atomicAdd(&bin_counts[t], cnt[t]);
}

__global__ __launch_bounds__(256) void scan256_k(const int* __restrict__ bin_counts,
                                                 int* __restrict__ binoffs,
                                                 int* __restrict__ gcur, int nbins) {
    __shared__ int sbuf[256];
    int t = threadIdx.x;
    int c = (t < nbins) ? bin_counts[t] : 0;
    sbuf[t] = c;
    __syncthreads();
    for (int off = 1; off < 256; off <<= 1) {
        int u = (t >= off) ? sbuf[t - off] : 0;
        __syncthreads();
        sbuf[t] += u;
        __syncthreads();
    }
    int ex = sbuf[t] - c;
    binoffs[t] = ex;
    if (t == 255) binoffs[256] = ex + c;
    gcur[t] = ex;
}

__global__ __launch_bounds__(256) void binify_k(const int* __restrict__ src,
                                                const int* __restrict__ dst,
                                                const float* __restrict__ w,
                                                int* __restrict__ gcur,
                                                int4* __restrict__ tmp, int E) {
    __shared__ int cnt[256];
    __shared__ int basearr[256];
    int t = threadIdx.x;
    cnt[t] = 0;
    __syncthreads();
    int base = blockIdx.x * EPB;
    int es[16], ed[16], ew[16];
    bool va[16];
    if (base + EPB <= E) {
        const int4* s4 = (const int4*)(src + base);
        const int4* d4 = (const int4*)(dst + base);
        const int4* w4 = (const int4*)(w + base);
        #pragma unroll
        for (int i = 0; i < 4; ++i) {
            int slot = i * 256 + t;
            int4 sv = s4[slot]; int4 dv = d4[slot]; int4 wv = w4[slot];
            es[i*4+0]=sv.x; es[i*4+1]=sv.y; es[i*4+2]=sv.z; es[i*4+3]=sv.w;
            ed[i*4+0]=dv.x; ed[i*4+1]=dv.y; ed[i*4+2]=dv.z; ed[i*4+3]=dv.w;
            ew[i*4+0]=wv.x; ew[i*4+1]=wv.y; ew[i*4+2]=wv.z; ew[i*4+3]=wv.w;
            va[i*4+0]=va[i*4+1]=va[i*4+2]=va[i*4+3]=true;
        }
    } else {
        #pragma unroll
        for (int i = 0; i < 4; ++i) {
            #pragma unroll
            for (int c = 0; c < 4; ++c) {
                int j = base + (i * 256 + t) * 4 + c;
                bool v = j < E;
                va[i*4+c] = v;
                es[i*4+c] = v ? src[j] : 0;
                ed[i*4+c] = v ? dst[j] : 0;
                ew[i*4+c] = v ? __float_as_int(w[j]) : 0;
            }
        }
    }
    #pragma unroll
    for (int i = 0; i < 16; ++i)
        if (va[i]) atomicAdd(&cnt[ed[i] >> BINSH], 1);
    __syncthreads();
    int c = cnt[t];
    basearr[t] = c ? atomicAdd(&gcur[t], c) : 0;
    __syncthreads();
    cnt[t] = 0;
    __syncthreads();
    #pragma unroll
    for (int i = 0; i < 16; ++i) {
        if (va[i]) {
            int b = ed[i] >> BINSH;
            int pos = atomicAdd(&cnt[b], 1);
            tmp[basearr[b] + pos] = make_int4(es[i], ew[i], ed[i], 0);
        }
    }
}

__global__ __launch_bounds__(256) void binfin_k(const int4* __restrict__ tmp,
                                                const int* __restrict__ binoffs,
                                                int* __restrict__ offs,
                                                int2* __restrict__ snw, int N, int E) {
    __shared__ int ncnt[512];
    __shared__ int noff[512];
    __shared__ int sbuf[256];
    int b = blockIdx.x, t = threadIdx.x;
    int lo = b << BINSH;
    int hi = min(lo + 512, N);
    int ebeg = binoffs[b], eend = binoffs[b + 1];
    ncnt[t] = 0; ncnt[t + 256] = 0;
    __syncthreads();
    for (int j = ebeg + t; j < eend; j += 256)
        atomicAdd(&ncnt[tmp[j].z - lo], 1);
    __syncthreads();
    int a0 = ncnt[2 * t], a1 = ncnt[2 * t + 1];
    sbuf[t] = a0 + a1;
    __syncthreads();
    for (int off = 1; off < 256; off <<= 1) {
        int u = (t >= off) ? sbuf[t - off] : 0;
        __syncthreads();
        sbuf[t] += u;
        __syncthreads();
    }
    int ex = sbuf[t] - (a0 + a1);
    noff[2 * t] = ex;
    noff[2 * t + 1] = ex + a0;
    if (lo + 2 * t     < hi) offs[lo + 2 * t]     = ebeg + ex;
    if (lo + 2 * t + 1 < hi) offs[lo + 2 * t + 1] = ebeg + ex + a0;
    if (b == 0 && t == 0) offs[N] = E;
    ncnt[t] = 0; ncnt[t + 256] = 0;
    __syncthreads();
    for (int j = ebeg + t; j < eend; j += 256) {
        int4 e = tmp[j];
        int idx = e.z - lo;
        int pos = atomicAdd(&ncnt[idx], 1);
        snw[ebeg + noff[idx] + pos] = make_int2(e.x, e.y);
    }
}

// ---------------- weight prep: transpose + bf16 convert ----------------
__global__ void prep_w_k(const float* __restrict__ W1, const float* __restrict__ W2,
                         const float* __restrict__ Wm, unsigned short* __restrict__ Wt1,
                         unsigned short* __restrict__ Wt2, unsigned short* __restrict__ Wtm) {
    int id = blockIdx.x * blockDim.x + threadIdx.x;
    if (id < 16384) {
        int k = id >> 7, c = id & 127;
        Wt1[c * 128 + k] = f2bf(W1[id]);
    } else if (id < 32768) {
        int e = id - 16384; int k = e >> 7, c = e & 127;
        Wt2[c * 128 + k] = f2bf(W2[e]);
    } else if (id < 65536) {
        int e = id - 32768;
        int k = e >> 7, c = e & 127;
        Wtm[c * 256 + k] = f2bf(Wm[e]);
    }
}

// ---------------- MFMA GEMM: C[M,128] = A[M,K] @ W[K,128] (+bias) ----------------
template<int K, bool A_F32, bool BIAS, bool OUT_BF16>
__global__ __launch_bounds__(256) void gemm_mfma(const void* __restrict__ A0v,
                                                 const void* __restrict__ A1v,
                                                 const unsigned short* __restrict__ Wt,
                                                 const float* __restrict__ bias,
                                                 void* __restrict__ Cv, int M) {
    __shared__ __align__(16) unsigned short At[128 * 128];
    __shared__ __align__(16) unsigned short Bt[128 * 128];
    const int t = threadIdx.x;
    const int lane = t & 63;
    const int wv = t >> 6;
    const int m0 = blockIdx.x * 128;
    const int l15 = lane & 15;
    const int l4 = lane >> 4;

    f32x4 acc[2][8];
    #pragma unroll
    for (int r = 0; r < 2; ++r)
        #pragma unroll
        for (int c = 0; c < 8; ++c) acc[r][c] = (f32x4){0.f, 0.f, 0.f, 0.f};

    const int srow = t >> 4;
    const int scol = (t & 15) * 8;

    for (int k0 = 0; k0 < K; k0 += 128) {
        const int chunk = k0 >> 7;
        #pragma unroll
        for (int p = 0; p < 8; ++p) {
            int row = p * 16 + srow;
            int gm = m0 + row;
            uint4 pk = make_uint4(0, 0, 0, 0);
            if (A_F32) {
                const float* Ap = (const float*)(chunk ? A1v : A0v);
                float4 f0 = make_float4(0.f,0.f,0.f,0.f), f1 = f0;
                if (gm < M) {
                    f0 = *(const float4*)(Ap + (size_t)gm * 128 + scol);
                    f1 = *(const float4*)(Ap + (size_t)gm * 128 + scol + 4);
                }
                pk.x = f2bf(f0.x) | ((unsigned)f2bf(f0.y) << 16);
                pk.y = f2bf(f0.z) | ((unsigned)f2bf(f0.w) << 16);
                pk.z = f2bf(f1.x) | ((unsigned)f2bf(f1.y) << 16);
                pk.w = f2bf(f1.z) | ((unsigned)f2bf(f1.w) << 16);
            } else {
                const unsigned short* Ap = (const unsigned short*)(chunk ? A1v : A0v);
                if (gm < M) pk = *(const uint4*)(Ap + (size_t)gm * 128 + scol);
            }
            int byte = (row * 256 + scol * 2) ^ ((row & 7) << 4);
            *(uint4*)((char*)At + byte) = pk;
        }
        #pragma unroll
        for (int p = 0; p < 8; ++p) {
            int row = p * 16 + srow;
            uint4 pk = *(const uint4*)(Wt + (size_t)row * K + k0 + scol);
            int byte = (row * 256 + scol * 2) ^ ((row & 7) << 4);
            *(uint4*)((char*)Bt + byte) = pk;
        }
        __syncthreads();
        #pragma unroll
        for (int ks = 0; ks < 4; ++ks) {
            int kb = ks * 32 + l4 * 8;
            bf16x8 af[2], bfv[8];
            #pragma unroll
            for (int r = 0; r < 2; ++r) {
                int row = wv * 32 + r * 16 + l15;
                int byte = (row * 256 + kb * 2) ^ ((row & 7) << 4);
                af[r] = *(const bf16x8*)((char*)At + byte);
            }
            #pragma unroll
            for (int c = 0; c < 8; ++c) {
                int col = c * 16 + l15;
                int byte = (col * 256 + kb * 2) ^ ((col & 7) << 4);
                bfv[c] = *(const bf16x8*)((char*)Bt + byte);
            }
            #pragma unroll
            for (int r = 0; r < 2; ++r)
                #pragma unroll
                for (int c = 0; c < 8; ++c)
                    acc[r][c] = __builtin_amdgcn_mfma_f32_16x16x32_bf16(af[r], bfv[c], acc[r][c], 0, 0, 0);
        }
        __syncthreads();
    }
    float bb[8];
    if (BIAS) {
        #pragma unroll
        for (int c = 0; c < 8; ++c) bb[c] = bias[c * 16 + l15];
    }
    #pragma unroll
    for (int r = 0; r < 2; ++r) {
        #pragma unroll
        for (int q = 0; q < 4; ++q) {
            int row = m0 + wv * 32 + r * 16 + l4 * 4 + q;
            if (row < M) {
                #pragma unroll
                for (int c = 0; c < 8; ++c) {
                    int col = c * 16 + l15;
                    float v = acc[r][c][q];
                    if (BIAS) v += bb[c];
                    if (OUT_BF16) ((unsigned short*)Cv)[(size_t)row * 128 + col] = f2bf(v);
                    else          ((float*)Cv)[(size_t)row * 128 + col] = v;
                }
            }
        }
    }
}

// ---------------- el/er ----------------
__global__ void elr_k(const __hip_bfloat16* __restrict__ ft, const float* __restrict__ al,
                      const float* __restrict__ ar, __hip_bfloat16* __restrict__ el,
                      __hip_bfloat16* __restrict__ er, int n) {
    int idx = blockIdx.x * blockDim.x + threadIdx.x;
    if (idx >= n * 8) return;
    int node = idx >> 3, h = idx & 7;
    const __hip_bfloat16* f = ft + (size_t)node * 128 + h * 16;
    uint4 a = *(const uint4*)f;
    uint4 b = *(const uint4*)(f + 8);
    float fv[16];
    fv[0]  = bf2f(a.x & 0xffff); fv[1]  = bf2f(a.x >> 16);
    fv[2]  = bf2f(a.y & 0xffff); fv[3]  = bf2f(a.y >> 16);
    fv[4]  = bf2f(a.z & 0xffff); fv[5]  = bf2f(a.z >> 16);
    fv[6]  = bf2f(a.w & 0xffff); fv[7]  = bf2f(a.w >> 16);
    fv[8]  = bf2f(b.x & 0xffff); fv[9]  = bf2f(b.x >> 16);
    fv[10] = bf2f(b.y & 0xffff); fv[11] = bf2f(b.y >> 16);
    fv[12] = bf2f(b.z & 0xffff); fv[13] = bf2f(b.z >> 16);
    fv[14] = bf2f(b.w & 0xffff); fv[15] = bf2f(b.w >> 16);
    float e1 = 0.f, e2 = 0.f;
    #pragma unroll
    for (int d = 0; d < 16; ++d) { e1 += fv[d] * al[h * 16 + d]; e2 += fv[d] * ar[h * 16 + d]; }
    unsigned short r1 = f2bf(e1), r2 = f2bf(e2);
    __builtin_memcpy(&el[idx], &r1, 2);
    __builtin_memcpy(&er[idx], &r2, 2);
}

// ---------------- aggregation v2: one wave per dst node ----------------
// LDS record rec[head][edge] = {byte_off(src*256), p}; gather loop is
// 1 ds_read_b64 + 1 v_add + 1 global_load + 2 unpack + 2 fma + 1 sum-add.
// Softmax denominator accumulated inside the gather loop (every lane sees
// every edge), eliminating the cross-lane butterfly entirely.
__global__ __launch_bounds__(256) void agg_k(const __hip_bfloat16* __restrict__ ftb,
                                             const __hip_bfloat16* __restrict__ el,
                                             const __hip_bfloat16* __restrict__ er,
                                             const int2* __restrict__ snw,
                                             const int* __restrict__ offs,
                                             unsigned short* __restrict__ out, int n) {
    // rec[wave][head][edge-slot] ; 65-pad makes reads conflict-free
    __shared__ int2 rec[4][8][65];
    int wid = threadIdx.x >> 6;
    int node = blockIdx.x * 4 + (threadIdx.x >> 6);
    if (node >= n) return;
    int lane = threadIdx.x & 63;
    int g8 = lane >> 3;                 // head this lane aggregates
    unsigned lane4 = (unsigned)(lane * 4);
    int beg = offs[node], end = offs[node + 1];
    int deg = end - beg;
    const char* fb = (const char*)ftb;

    float erv[8];
    {
        uint4 u = *(const uint4*)(er + (size_t)node * 8);
        erv[0] = bf2f(u.x & 0xffff); erv[1] = bf2f(u.x >> 16);
        erv[2] = bf2f(u.y & 0xffff); erv[3] = bf2f(u.y >> 16);
        erv[4] = bf2f(u.z & 0xffff); erv[5] = bf2f(u.z >> 16);
        erv[6] = bf2f(u.w & 0xffff); erv[7] = bf2f(u.w >> 16);
    }

    float acc0 = 0.f, acc1 = 0.f, s = 0.f;

    for (int c0 = 0; c0 < deg; c0 += 64) {
        int cnt = min(64, deg - c0);
        if (lane < cnt) {
            int2 p2 = snw[beg + c0 + lane];          // coalesced 8B
            int off = p2.x << 8;                     // src * 256 bytes
            float wv = __int_as_float(p2.y);
            uint4 u = *(const uint4*)(el + (size_t)p2.x * 8);   // L2-resident gather
            float elv[8];
            elv[0] = bf2f(u.x & 0xffff); elv[1] = bf2f(u.x >> 16);
            elv[2] = bf2f(u.y & 0xffff); elv[3] = bf2f(u.y >> 16);
            elv[4] = bf2f(u.z & 0xffff); elv[5] = bf2f(u.z >> 16);
            elv[6] = bf2f(u.w & 0xffff); elv[7] = bf2f(u.w >> 16);
            #pragma unroll
            for (int h = 0; h < 8; ++h) {
                float tt = elv[h] + erv[h];
                tt = tt > 0.f ? tt : NEG_SLOPE * tt;
                float p = __expf(tt * wv);
                rec[wid][h][lane] = make_int2(off, __float_as_int(p));
            }
        }
        __builtin_amdgcn_wave_barrier();
        asm volatile("s_waitcnt lgkmcnt(0)" ::: "memory");
        __builtin_amdgcn_wave_barrier();

        #pragma unroll 4
        for (int j = 0; j < cnt; ++j) {
            int2 r = rec[wid][g8][j];               // ds_read_b64, broadcast per 8 lanes
            float a = __int_as_float(r.y);
            unsigned vo = (unsigned)r.x + lane4;
            unsigned u = *(const unsigned*)(fb + vo);   // saddr + 32-bit voffset
            s += a;
            acc0 += a * bf2f(u & 0xffff);
            acc1 += a * bf2f(u >> 16);
        }
        __builtin_amdgcn_wave_barrier();
    }

    float sinv = s > 0.f ? 1.f / s : 0.f;
    float o0 = fmaxf(acc0 * sinv, 0.f);
    float o1 = fmaxf(acc1 * sinv, 0.f);
    unsigned pk = f2bf(o0) | ((unsigned)f2bf(o1) << 16);
    *(unsigned*)(out + (size_t)node * 128 + lane * 2) = pk;
}

extern "C" void kernel_launch(void* const* d_in, const int* in_sizes, int n_in,
                              void* d_out, int out_size, void* d_ws, size_t ws_size,
                              hipStream_t stream) {
    const float* features = (const float*)d_in[0];
    const int*   src      = (const int*)d_in[1];
    const int*   dst      = (const int*)d_in[2];
    const float* w        = (const float*)d_in[3];
    const float* W1       = (const float*)d_in[4];
    const float* al1      = (const float*)d_in[5];
    const float* ar1      = (const float*)d_in[6];
    const float* W2       = (const float*)d_in[7];
    const float* al2      = (const float*)d_in[8];
    const float* ar2      = (const float*)d_in[9];
    const float* Wm       = (const float*)d_in[10];
    const float* bm       = (const float*)d_in[11];
    float* out = (float*)d_out;

    const int N = in_sizes[0] / 128;
    const int E = in_sizes[1];

    char* ws = (char*)d_ws;
    unsigned short* ftb = (unsigned short*)ws;            ws += (size_t)N * 128 * 2;
    unsigned short* x1b = (unsigned short*)ws;            ws += (size_t)N * 128 * 2;
    unsigned short* x2b = (unsigned short*)ws;            ws += (size_t)N * 128 * 2;
    unsigned short* el  = (unsigned short*)ws;            ws += (size_t)N * 8 * 2;
    unsigned short* er  = (unsigned short*)ws;            ws += (size_t)N * 8 * 2;
    unsigned short* Wt1 = (unsigned short*)ws;            ws += (size_t)128 * 128 * 2;
    unsigned short* Wt2 = (unsigned short*)ws;            ws += (size_t)128 * 128 * 2;
    unsigned short* Wtm = (unsigned short*)ws;            ws += (size_t)128 * 256 * 2;
    int* offs      = (int*)ws;                            ws += (size_t)(N + 4) * 4;
    int* bin_counts= (int*)ws;                            ws += 256 * 4;
    int* binoffs   = (int*)ws;                            ws += 260 * 4;
    int* gcur      = (int*)ws;                            ws += 256 * 4;
    int2* snw      = (int2*)ws;                           ws += (size_t)E * 8;
    // tmp aliases x1b/x2b (used only during CSR build, before layer 1 writes x1b)
    int4* tmp = (int4*)x1b;

    hipMemsetAsync(bin_counts, 0, 256 * sizeof(int), stream);

    const int nbins = (N + 511) >> BINSH;
    const int nblk_e = (E + EPB - 1) / EPB;

    prep_w_k<<<256, 256, 0, stream>>>(W1, W2, Wm, Wt1, Wt2, Wtm);

    binhist_k<<<nblk_e, 256, 0, stream>>>(dst, bin_counts, E);
    scan256_k<<<1, 256, 0, stream>>>(bin_counts, binoffs, gcur, nbins);
    binify_k<<<nblk_e, 256, 0, stream>>>(src, dst, w, gcur, tmp, E);
    binfin_k<<<nbins, 256, 0, stream>>>(tmp, binoffs, offs, snw, N, E);

    int gemm_grid = (N + 127) / 128;
    int agg_grid = (N + 3) / 4;

    // ---- layer 1 ----
    gemm_mfma<128, true, false, true><<<gemm_grid, 256, 0, stream>>>(features, nullptr, Wt1, nullptr, ftb, N);
    elr_k<<<(N * 8 + 255) / 256, 256, 0, stream>>>((const __hip_bfloat16*)ftb, al1, ar1,
                                                   (__hip_bfloat16*)el, (__hip_bfloat16*)er, N);
    agg_k<<<agg_grid, 256, 0, stream>>>((const __hip_bfloat16*)ftb, (const __hip_bfloat16*)el,
                                        (const __hip_bfloat16*)er, snw, offs, x1b, N);

    // ---- layer 2 ----
    gemm_mfma<128, false, false, true><<<gemm_grid, 256, 0, stream>>>(x1b, nullptr, Wt2, nullptr, ftb, N);
    elr_k<<<(N * 8 + 255) / 256, 256, 0, stream>>>((const __hip_bfloat16*)ftb, al2, ar2,
                                                   (__hip_bfloat16*)el, (__hip_bfloat16*)er, N);
    agg_k<<<agg_grid, 256, 0, stream>>>((const __hip_bfloat16*)ftb, (const __hip_bfloat16*)el,
                                        (const __hip_bfloat16*)er, snw, offs, x2b, N);

    // ---- final: [x1|x2] @ Wm + bm (f32 out) ----
    gemm_mfma<256, false, true, false><<<gemm_grid, 256, 0, stream>>>(x1b, x2b, Wtm, bm, out, N);
}